// Round 1
// baseline (426.609 us; speedup 1.0000x reference)
//
#include <hip/hip_runtime.h>
#include <math.h>

#define BHN   64
#define SEQ   4096
#define DIM   64
#define NCHUNK 16
#define CHUNK (SEQ / NCHUNK)   // 256 rows per pass-1 block
#define STG   8                // rows staged in LDS at a time
#define RPB   128              // rows per pass-2 block (4 waves x 32)

// ---------------- Pass 1: kv[bh][128][64] and ksum[bh][128] ----------------
__global__ __launch_bounds__(256) void cosformer_kv(
    const float* __restrict__ K, const float* __restrict__ V,
    float* __restrict__ kv, float* __restrict__ ksum)
{
    __shared__ float rk[STG][DIM];   // relu(K) rows
    __shared__ float vv[STG][DIM];   // V rows
    __shared__ float cs[STG], sn[STG];

    const int bh    = blockIdx.x / NCHUNK;
    const int chunk = blockIdx.x % NCHUNK;
    const int row0  = chunk * CHUNK;
    const float* Kb = K + (size_t)bh * SEQ * DIM;
    const float* Vb = V + (size_t)bh * SEQ * DIM;

    const int tid = threadIdx.x;
    const int td  = tid & 31;   // d-lane: owns d = td, td+32 (cos) / +64, +96 (sin)
    const int tm  = tid >> 5;   // m-group: owns m = tm + 8*j

    float acc[4][8];
    #pragma unroll
    for (int i = 0; i < 4; ++i)
        #pragma unroll
        for (int j = 0; j < 8; ++j) acc[i][j] = 0.f;
    float aks[4] = {0.f, 0.f, 0.f, 0.f};

    for (int s0 = 0; s0 < CHUNK; s0 += STG) {
        __syncthreads();  // protect LDS reuse from previous iteration
        if (tid < 128) {
            // 8 rows x 64 floats of K, contiguous: 128 float4
            float4 kq = ((const float4*)(Kb + (size_t)(row0 + s0) * DIM))[tid];
            float* dst = &rk[0][0] + tid * 4;
            dst[0] = fmaxf(kq.x, 0.f);
            dst[1] = fmaxf(kq.y, 0.f);
            dst[2] = fmaxf(kq.z, 0.f);
            dst[3] = fmaxf(kq.w, 0.f);
        } else {
            int t = tid - 128;
            float4 vq = ((const float4*)(Vb + (size_t)(row0 + s0) * DIM))[t];
            float* dst = &vv[0][0] + t * 4;
            dst[0] = vq.x; dst[1] = vq.y; dst[2] = vq.z; dst[3] = vq.w;
        }
        if (tid < STG) {
            int l = row0 + s0 + tid;
            float ang = 1.5707963267948966f * (float)(l + 1) / (float)SEQ;
            float s_, c_;
            __sincosf(ang, &s_, &c_);
            cs[tid] = c_; sn[tid] = s_;
        }
        __syncthreads();

        #pragma unroll
        for (int r = 0; r < STG; ++r) {
            float k0 = rk[r][td], k1 = rk[r][td + 32];
            float c = cs[r], s = sn[r];
            float f0 = k0 * c, f1 = k1 * c, f2 = k0 * s, f3 = k1 * s;
            float vr[8];
            #pragma unroll
            for (int j = 0; j < 8; ++j) vr[j] = vv[r][tm + 8 * j];
            #pragma unroll
            for (int j = 0; j < 8; ++j) {
                acc[0][j] += f0 * vr[j];
                acc[1][j] += f1 * vr[j];
                acc[2][j] += f2 * vr[j];
                acc[3][j] += f3 * vr[j];
            }
            if (tm == 0) { aks[0] += f0; aks[1] += f1; aks[2] += f2; aks[3] += f3; }
        }
    }

    float* kvb = kv + (size_t)bh * 128 * DIM;
    const int dmap[4] = { td, td + 32, td + 64, td + 96 };
    #pragma unroll
    for (int i = 0; i < 4; ++i)
        #pragma unroll
        for (int j = 0; j < 8; ++j)
            atomicAdd(&kvb[dmap[i] * DIM + tm + 8 * j], acc[i][j]);
    if (tm == 0) {
        #pragma unroll
        for (int i = 0; i < 4; ++i) atomicAdd(&ksum[bh * 128 + dmap[i]], aks[i]);
    }
}

// ---------------- Pass 2: out = (q_cs @ kv) * norm ----------------
__global__ __launch_bounds__(256) void cosformer_out(
    const float* __restrict__ Q, const float* __restrict__ kv,
    const float* __restrict__ ksum, float* __restrict__ out)
{
    __shared__ float skv[128][DIM];    // 32 KB: rows 0..63 = cos-half, 64..127 = sin-half
    __shared__ float sks[128];
    __shared__ float srq[4][4][DIM];   // per-wave broadcast buffer, 4 rows

    const int nt   = SEQ / RPB;        // 32 tiles per head
    const int bh   = blockIdx.x / nt;
    const int tile = blockIdx.x % nt;
    const int row0 = tile * RPB;

    const int tid = threadIdx.x;
    const float* kvb = kv + (size_t)bh * 128 * DIM;
    #pragma unroll
    for (int i = 0; i < 8; ++i)
        ((float4*)&skv[0][0])[tid + 256 * i] = ((const float4*)kvb)[tid + 256 * i];
    if (tid < 128) sks[tid] = ksum[bh * 128 + tid];
    __syncthreads();

    const int wid  = tid >> 6;
    const int lane = tid & 63;         // = output column m, also d-index for denom partial
    const float* Qb = Q + (size_t)bh * SEQ * DIM;
    float* Ob = out + (size_t)bh * SEQ * DIM;
    const int wrow = row0 + wid * 32;

    for (int g = 0; g < 32; g += 4) {
        float rq[4], c[4], s[4];
        #pragma unroll
        for (int r = 0; r < 4; ++r) {
            int l = wrow + g + r;
            float qv = Qb[(size_t)l * DIM + lane];
            rq[r] = fmaxf(qv, 0.f) * 0.125f;   // relu(q)/sqrt(D)
            srq[wid][r][lane] = rq[r];
            float ang = 1.5707963267948966f * (float)(l + 1) / (float)SEQ;
            __sincosf(ang, &s[r], &c[r]);
        }
        __syncthreads();

        float ac[4] = {0.f, 0.f, 0.f, 0.f};
        float as_[4] = {0.f, 0.f, 0.f, 0.f};
        #pragma unroll 8
        for (int d = 0; d < 64; ++d) {
            float kc = skv[d][lane];        // cos-half kv
            float kd = skv[d + 64][lane];   // sin-half kv
            float r0 = srq[wid][0][d];
            float r1 = srq[wid][1][d];
            float r2 = srq[wid][2][d];
            float r3 = srq[wid][3][d];
            ac[0] += r0 * kc;  as_[0] += r0 * kd;
            ac[1] += r1 * kc;  as_[1] += r1 * kd;
            ac[2] += r2 * kc;  as_[2] += r2 * kd;
            ac[3] += r3 * kc;  as_[3] += r3 * kd;
        }

        #pragma unroll
        for (int r = 0; r < 4; ++r) {
            int l = wrow + g + r;
            // denominator: q_cs . k_sum, per-lane partial + 64-lane butterfly
            float dp = rq[r] * (c[r] * sks[lane] + s[r] * sks[lane + 64]);
            #pragma unroll
            for (int off = 32; off > 0; off >>= 1) dp += __shfl_xor(dp, off);
            float den = fmaxf(dp, 1e-6f);
            Ob[(size_t)l * DIM + lane] = (c[r] * ac[r] + s[r] * as_[r]) / den;
        }
        __syncthreads();  // protect srq before next group's writes
    }
}

extern "C" void kernel_launch(void* const* d_in, const int* in_sizes, int n_in,
                              void* d_out, int out_size, void* d_ws, size_t ws_size,
                              hipStream_t stream) {
    const float* Q = (const float*)d_in[0];
    const float* K = (const float*)d_in[1];
    const float* V = (const float*)d_in[2];
    float* out = (float*)d_out;

    float* kv = (float*)d_ws;                      // [64][128][64]
    float* ks = kv + (size_t)BHN * 128 * DIM;      // [64][128]
    size_t zbytes = (size_t)(BHN * 128 * DIM + BHN * 128) * sizeof(float);
    hipMemsetAsync(d_ws, 0, zbytes, stream);

    hipLaunchKernelGGL(cosformer_kv, dim3(BHN * NCHUNK), dim3(256), 0, stream,
                       K, V, kv, ks);
    hipLaunchKernelGGL(cosformer_out, dim3(BHN * (SEQ / RPB)), dim3(256), 0, stream,
                       Q, kv, ks, out);
}

// Round 2
// 190.447 us; speedup vs baseline: 2.2400x; 2.2400x over previous
//
#include <hip/hip_runtime.h>
#include <math.h>

#define BHN    64
#define SEQ    4096
#define DIM    64
#define NCHUNK 16
#define CHUNK  (SEQ / NCHUNK)        // 256 rows per pass-1 block
#define STG    16                    // rows per stage
#define NSTAGE (CHUNK / STG)         // 16 stages
#define RPB    128                   // rows per pass-2 block (4 waves x 32)
#define KVF    (128 * DIM)           // 8192 floats of kv per head
// per-chunk partial region: [64 heads][8192 kv] + [64 heads][128 ksum]
#define STRIDE_C ((size_t)BHN * KVF + (size_t)BHN * 128)   // 532480 floats

// ---------------- Pass 1: partial kv/ksum per (head, chunk) ----------------
template<int USE_ATOMIC>
__global__ __launch_bounds__(256) void cosformer_kv(
    const float* __restrict__ K, const float* __restrict__ V,
    float* __restrict__ part)
{
    __shared__ float  rk[2][STG][DIM];   // relu(K) rows, double-buffered
    __shared__ float  vv[2][STG][DIM];   // V rows
    __shared__ float2 tg[2][STG];        // (cos, sin) per row

    const int bh    = blockIdx.x / NCHUNK;
    const int chunk = blockIdx.x % NCHUNK;
    const int row0  = chunk * CHUNK;
    const float* Kb = K + (size_t)bh * SEQ * DIM;
    const float* Vb = V + (size_t)bh * SEQ * DIM;

    const int tid = threadIdx.x;
    const int td  = tid & 31;   // owns d = 2td, 2td+1 (cos) / +64 (sin)
    const int tm  = tid >> 5;   // owns m = tm*8 .. tm*8+7

    float acc[4][8];
    #pragma unroll
    for (int i = 0; i < 4; ++i)
        #pragma unroll
        for (int j = 0; j < 8; ++j) acc[i][j] = 0.f;
    float aks[4] = {0.f, 0.f, 0.f, 0.f};

    // prologue: stage 0 into buffer 0 (16 rows = 256 float4 per array)
    {
        float4 kq = ((const float4*)(Kb + (size_t)row0 * DIM))[tid];
        float4 vq = ((const float4*)(Vb + (size_t)row0 * DIM))[tid];
        ((float4*)&rk[0][0][0])[tid] =
            make_float4(fmaxf(kq.x, 0.f), fmaxf(kq.y, 0.f),
                        fmaxf(kq.z, 0.f), fmaxf(kq.w, 0.f));
        ((float4*)&vv[0][0][0])[tid] = vq;
        if (tid < STG) {
            float ang = 1.5707963267948966f * (float)(row0 + tid + 1) / (float)SEQ;
            float s_, c_;
            __sincosf(ang, &s_, &c_);
            tg[0][tid] = make_float2(c_, s_);
        }
    }

    int cur = 0;
    for (int s = 0; s < NSTAGE; ++s) {
        __syncthreads();    // buf[cur] ready; prior readers of buf[cur^1] done

        // prefetch next stage into registers (latency hides under compute)
        float4 kq, vq;
        const bool pf = (s + 1 < NSTAGE);
        if (pf) {
            const float* kp = Kb + (size_t)(row0 + (s + 1) * STG) * DIM;
            const float* vp = Vb + (size_t)(row0 + (s + 1) * STG) * DIM;
            kq = ((const float4*)kp)[tid];
            vq = ((const float4*)vp)[tid];
        }

        #pragma unroll
        for (int r = 0; r < STG; ++r) {
            float2 kk = *(const float2*)&rk[cur][r][2 * td];   // ds_read_b64
            float2 tr = tg[cur][r];                            // broadcast
            float4 va = *(const float4*)&vv[cur][r][tm * 8];       // b128 bcast
            float4 vb = *(const float4*)&vv[cur][r][tm * 8 + 4];
            float f0 = kk.x * tr.x, f1 = kk.y * tr.x;
            float f2 = kk.x * tr.y, f3 = kk.y * tr.y;
            float vr[8] = {va.x, va.y, va.z, va.w, vb.x, vb.y, vb.z, vb.w};
            #pragma unroll
            for (int j = 0; j < 8; ++j) {
                acc[0][j] += f0 * vr[j];
                acc[1][j] += f1 * vr[j];
                acc[2][j] += f2 * vr[j];
                acc[3][j] += f3 * vr[j];
            }
            if (tm == 0) { aks[0] += f0; aks[1] += f1; aks[2] += f2; aks[3] += f3; }
        }

        if (pf) {
            int nb = cur ^ 1;
            ((float4*)&rk[nb][0][0])[tid] =
                make_float4(fmaxf(kq.x, 0.f), fmaxf(kq.y, 0.f),
                            fmaxf(kq.z, 0.f), fmaxf(kq.w, 0.f));
            ((float4*)&vv[nb][0][0])[tid] = vq;
            if (tid < STG) {
                int l = row0 + (s + 1) * STG + tid;
                float ang = 1.5707963267948966f * (float)(l + 1) / (float)SEQ;
                float s_, c_;
                __sincosf(ang, &s_, &c_);
                tg[nb][tid] = make_float2(c_, s_);
            }
        }
        cur ^= 1;
    }

    const int dmap[4] = { 2 * td, 2 * td + 1, 64 + 2 * td, 64 + 2 * td + 1 };
    if (USE_ATOMIC) {
        float* kvb = part + (size_t)bh * KVF;
        #pragma unroll
        for (int i = 0; i < 4; ++i)
            #pragma unroll
            for (int j = 0; j < 8; ++j)
                atomicAdd(&kvb[dmap[i] * DIM + tm * 8 + j], acc[i][j]);
        if (tm == 0) {
            float* ks = part + (size_t)BHN * KVF + bh * 128;
            #pragma unroll
            for (int i = 0; i < 4; ++i) atomicAdd(&ks[dmap[i]], aks[i]);
        }
    } else {
        float* pb = part + STRIDE_C * chunk + (size_t)bh * KVF;
        #pragma unroll
        for (int i = 0; i < 4; ++i) {
            *(float4*)&pb[dmap[i] * DIM + tm * 8] =
                make_float4(acc[i][0], acc[i][1], acc[i][2], acc[i][3]);
            *(float4*)&pb[dmap[i] * DIM + tm * 8 + 4] =
                make_float4(acc[i][4], acc[i][5], acc[i][6], acc[i][7]);
        }
        if (tm == 0) {
            float* ps = part + STRIDE_C * chunk + (size_t)BHN * KVF + bh * 128;
            #pragma unroll
            for (int i = 0; i < 4; ++i) ps[dmap[i]] = aks[i];
        }
    }
}

// ---------------- Reduce: sum the 16 chunk partials ----------------
__global__ __launch_bounds__(256) void reduce_part(
    const float* __restrict__ part, float* __restrict__ fin)
{
    size_t o = (size_t)blockIdx.x * 256 + threadIdx.x;
    float s = 0.f;
    #pragma unroll
    for (int c = 0; c < NCHUNK; ++c) s += part[(size_t)c * STRIDE_C + o];
    fin[o] = s;
}

// ---------------- Pass 2: out = (q_cs @ kv) * norm ----------------
__global__ __launch_bounds__(256) void cosformer_out(
    const float* __restrict__ Q, const float* __restrict__ kv,
    const float* __restrict__ ksum, float* __restrict__ out)
{
    __shared__ float skv[128][DIM];    // 32 KB
    __shared__ float sks[128];
    __shared__ float srq[4][4][DIM];   // per-wave broadcast, 4 rows

    const int nt   = SEQ / RPB;        // 32 tiles per head
    const int bh   = blockIdx.x / nt;
    const int tile = blockIdx.x % nt;
    const int row0 = tile * RPB;

    const int tid = threadIdx.x;
    const float* kvb = kv + (size_t)bh * KVF;
    #pragma unroll
    for (int i = 0; i < 8; ++i)
        ((float4*)&skv[0][0])[tid + 256 * i] = ((const float4*)kvb)[tid + 256 * i];
    if (tid < 128) sks[tid] = ksum[bh * 128 + tid];

    const int wid  = tid >> 6;
    const int lane = tid & 63;
    const float* Qb = Q + (size_t)bh * SEQ * DIM;
    float* Ob = out + (size_t)bh * SEQ * DIM;
    const int wrow = row0 + wid * 32;

    float qv[4];
    #pragma unroll
    for (int r = 0; r < 4; ++r)
        qv[r] = Qb[(size_t)(wrow + r) * DIM + lane];

    for (int g = 0; g < 32; g += 4) {
        float rq[4], c[4], s[4];
        #pragma unroll
        for (int r = 0; r < 4; ++r) {
            int l = wrow + g + r;
            rq[r] = fmaxf(qv[r], 0.f) * 0.125f;   // relu(q)/sqrt(D)
            srq[wid][r][lane] = rq[r];
            float ang = 1.5707963267948966f * (float)(l + 1) / (float)SEQ;
            __sincosf(ang, &s[r], &c[r]);
        }
        __syncthreads();   // srq (and, first iter, skv/sks) visible

        if (g + 4 < 32) {  // prefetch next group's Q under the d-loop
            #pragma unroll
            for (int r = 0; r < 4; ++r)
                qv[r] = Qb[(size_t)(wrow + g + 4 + r) * DIM + lane];
        }

        float ac[4] = {0.f, 0.f, 0.f, 0.f};
        float as_[4] = {0.f, 0.f, 0.f, 0.f};
        #pragma unroll 8
        for (int d = 0; d < 64; ++d) {
            float kc = skv[d][lane];
            float kd = skv[d + 64][lane];
            float r0 = srq[wid][0][d];
            float r1 = srq[wid][1][d];
            float r2 = srq[wid][2][d];
            float r3 = srq[wid][3][d];
            ac[0] += r0 * kc;  as_[0] += r0 * kd;
            ac[1] += r1 * kc;  as_[1] += r1 * kd;
            ac[2] += r2 * kc;  as_[2] += r2 * kd;
            ac[3] += r3 * kc;  as_[3] += r3 * kd;
        }

        #pragma unroll
        for (int r = 0; r < 4; ++r) {
            int l = wrow + g + r;
            float dp = rq[r] * (c[r] * sks[lane] + s[r] * sks[lane + 64]);
            #pragma unroll
            for (int off = 32; off > 0; off >>= 1) dp += __shfl_xor(dp, off);
            float den = fmaxf(dp, 1e-6f);
            Ob[(size_t)l * DIM + lane] = (c[r] * ac[r] + s[r] * as_[r]) / den;
        }
        __syncthreads();   // srq readers done before next group's writes
    }
}

extern "C" void kernel_launch(void* const* d_in, const int* in_sizes, int n_in,
                              void* d_out, int out_size, void* d_ws, size_t ws_size,
                              hipStream_t stream) {
    const float* Q = (const float*)d_in[0];
    const float* K = (const float*)d_in[1];
    const float* V = (const float*)d_in[2];
    float* out = (float*)d_out;
    float* ws  = (float*)d_ws;

    const size_t need = (size_t)(NCHUNK + 1) * STRIDE_C * sizeof(float);
    if (ws_size >= need) {
        // partial path: no atomics
        float* part = ws;
        float* fin  = ws + (size_t)NCHUNK * STRIDE_C;
        hipLaunchKernelGGL(cosformer_kv<0>, dim3(BHN * NCHUNK), dim3(256), 0, stream,
                           K, V, part);
        hipLaunchKernelGGL(reduce_part, dim3((int)(STRIDE_C / 256)), dim3(256), 0, stream,
                           part, fin);
        hipLaunchKernelGGL(cosformer_out, dim3(BHN * (SEQ / RPB)), dim3(256), 0, stream,
                           Q, fin, fin + (size_t)BHN * KVF, out);
    } else {
        // fallback: atomic accumulation into zeroed final buffer
        float* fin = ws;
        hipMemsetAsync(fin, 0, STRIDE_C * sizeof(float), stream);
        hipLaunchKernelGGL(cosformer_kv<1>, dim3(BHN * NCHUNK), dim3(256), 0, stream,
                           K, V, fin);
        hipLaunchKernelGGL(cosformer_out, dim3(BHN * (SEQ / RPB)), dim3(256), 0, stream,
                           Q, fin, fin + (size_t)BHN * KVF, out);
    }
}

// Round 3
// 120.315 us; speedup vs baseline: 3.5458x; 1.5829x over previous
//
#include <hip/hip_runtime.h>
#include <hip/hip_bf16.h>
#include <math.h>

#define BHN    64
#define SEQ    4096
#define DIM    64
#define NCHUNK 16
#define CHUNK  (SEQ / NCHUNK)        // 256 rows per pass-1 block
#define STG    16                    // rows per stage
#define NSTAGE (CHUNK / STG)         // 16 stages
#define KVF    (128 * DIM)           // 8192 floats of kv per head
#define STRIDE_C ((size_t)BHN * KVF + (size_t)BHN * 128)   // 532480 floats
#define KSBASE ((size_t)BHN * KVF)   // 524288
#define FRAGH  10240                 // bf16 per head: 5 t * 4 ks * 64 lanes * 8 j

typedef __bf16 bf16x8v __attribute__((ext_vector_type(8)));
typedef float  f32x4v  __attribute__((ext_vector_type(4)));

__device__ inline f32x4v mfma16(bf16x8v a, bf16x8v b, f32x4v c) {
    return __builtin_amdgcn_mfma_f32_16x16x32_bf16(a, b, c, 0, 0, 0);
}

// ---------------- Pass 1: partial kv/ksum per (head, chunk) ----------------
template<int USE_ATOMIC>
__global__ __launch_bounds__(256) void cosformer_kv(
    const float* __restrict__ K, const float* __restrict__ V,
    float* __restrict__ part)
{
    __shared__ float  rk[2][STG][DIM];
    __shared__ float  vv[2][STG][DIM];
    __shared__ float2 tg[2][STG];

    const int bh    = blockIdx.x / NCHUNK;
    const int chunk = blockIdx.x % NCHUNK;
    const int row0  = chunk * CHUNK;
    const float* Kb = K + (size_t)bh * SEQ * DIM;
    const float* Vb = V + (size_t)bh * SEQ * DIM;

    const int tid = threadIdx.x;
    const int td  = tid & 31;
    const int tm  = tid >> 5;

    float acc[4][8];
    #pragma unroll
    for (int i = 0; i < 4; ++i)
        #pragma unroll
        for (int j = 0; j < 8; ++j) acc[i][j] = 0.f;
    float aks[4] = {0.f, 0.f, 0.f, 0.f};

    {
        float4 kq = ((const float4*)(Kb + (size_t)row0 * DIM))[tid];
        float4 vq = ((const float4*)(Vb + (size_t)row0 * DIM))[tid];
        ((float4*)&rk[0][0][0])[tid] =
            make_float4(fmaxf(kq.x, 0.f), fmaxf(kq.y, 0.f),
                        fmaxf(kq.z, 0.f), fmaxf(kq.w, 0.f));
        ((float4*)&vv[0][0][0])[tid] = vq;
        if (tid < STG) {
            float ang = 1.5707963267948966f * (float)(row0 + tid + 1) / (float)SEQ;
            float s_, c_;
            __sincosf(ang, &s_, &c_);
            tg[0][tid] = make_float2(c_, s_);
        }
    }

    int cur = 0;
    for (int s = 0; s < NSTAGE; ++s) {
        __syncthreads();

        float4 kq, vq;
        const bool pf = (s + 1 < NSTAGE);
        if (pf) {
            const float* kp = Kb + (size_t)(row0 + (s + 1) * STG) * DIM;
            const float* vp = Vb + (size_t)(row0 + (s + 1) * STG) * DIM;
            kq = ((const float4*)kp)[tid];
            vq = ((const float4*)vp)[tid];
        }

        #pragma unroll
        for (int r = 0; r < STG; ++r) {
            float2 kk = *(const float2*)&rk[cur][r][2 * td];
            float2 tr = tg[cur][r];
            float4 va = *(const float4*)&vv[cur][r][tm * 8];
            float4 vb = *(const float4*)&vv[cur][r][tm * 8 + 4];
            float f0 = kk.x * tr.x, f1 = kk.y * tr.x;
            float f2 = kk.x * tr.y, f3 = kk.y * tr.y;
            float vr[8] = {va.x, va.y, va.z, va.w, vb.x, vb.y, vb.z, vb.w};
            #pragma unroll
            for (int j = 0; j < 8; ++j) {
                acc[0][j] += f0 * vr[j];
                acc[1][j] += f1 * vr[j];
                acc[2][j] += f2 * vr[j];
                acc[3][j] += f3 * vr[j];
            }
            if (tm == 0) { aks[0] += f0; aks[1] += f1; aks[2] += f2; aks[3] += f3; }
        }

        if (pf) {
            int nb = cur ^ 1;
            ((float4*)&rk[nb][0][0])[tid] =
                make_float4(fmaxf(kq.x, 0.f), fmaxf(kq.y, 0.f),
                            fmaxf(kq.z, 0.f), fmaxf(kq.w, 0.f));
            ((float4*)&vv[nb][0][0])[tid] = vq;
            if (tid < STG) {
                int l = row0 + (s + 1) * STG + tid;
                float ang = 1.5707963267948966f * (float)(l + 1) / (float)SEQ;
                float s_, c_;
                __sincosf(ang, &s_, &c_);
                tg[nb][tid] = make_float2(c_, s_);
            }
        }
        cur ^= 1;
    }

    const int dmap[4] = { 2 * td, 2 * td + 1, 64 + 2 * td, 64 + 2 * td + 1 };
    if (USE_ATOMIC) {
        float* kvb = part + (size_t)bh * KVF;
        #pragma unroll
        for (int i = 0; i < 4; ++i)
            #pragma unroll
            for (int j = 0; j < 8; ++j)
                atomicAdd(&kvb[dmap[i] * DIM + tm * 8 + j], acc[i][j]);
        if (tm == 0) {
            float* ks = part + KSBASE + bh * 128;
            #pragma unroll
            for (int i = 0; i < 4; ++i) atomicAdd(&ks[dmap[i]], aks[i]);
        }
    } else {
        float* pb = part + STRIDE_C * chunk + (size_t)bh * KVF;
        #pragma unroll
        for (int i = 0; i < 4; ++i) {
            *(float4*)&pb[dmap[i] * DIM + tm * 8] =
                make_float4(acc[i][0], acc[i][1], acc[i][2], acc[i][3]);
            *(float4*)&pb[dmap[i] * DIM + tm * 8 + 4] =
                make_float4(acc[i][4], acc[i][5], acc[i][6], acc[i][7]);
        }
        if (tm == 0) {
            float* ps = part + STRIDE_C * chunk + KSBASE + bh * 128;
            #pragma unroll
            for (int i = 0; i < 4; ++i) ps[dmap[i]] = aks[i];
        }
    }
}

// ------- Reduce + pack into bf16 B-fragment layout for pass-2 MFMA -------
// bfrag[head][t][ks][lane][j]: B[k][n], k=ks*32+(lane>>4)*8+j, n=t*16+(lane&15)
// t=0..3: kv columns; t=4 col 0: ksum (denominator), other cols zero (memset).
template<int NC>
__global__ __launch_bounds__(256) void reduce_pack(
    const float* __restrict__ part, __hip_bfloat16* __restrict__ bfrag)
{
    size_t o = (size_t)blockIdx.x * 256 + threadIdx.x;
    float s = 0.f;
    #pragma unroll
    for (int c = 0; c < NC; ++c) s += part[(size_t)c * STRIDE_C + o];
    if (o < KSBASE) {
        int head = (int)(o >> 13);
        int r = (int)(o & 8191);
        int k = r >> 6, n = r & 63;
        int t = n >> 4, ks = k >> 5, lg = (k >> 3) & 3, j = k & 7;
        int lane = lg * 16 + (n & 15);
        bfrag[(size_t)head * FRAGH + (size_t)(((t * 4 + ks) * 64 + lane) * 8 + j)] =
            __float2bfloat16(s);
    } else {
        int r = (int)(o - KSBASE);
        int head = r >> 7, k = r & 127;
        int ks = k >> 5, lg = (k >> 3) & 3, j = k & 7;
        bfrag[(size_t)head * FRAGH + (size_t)(((16 + ks) * 64 + lg * 16) * 8 + j)] =
            __float2bfloat16(s);
    }
}

// ---------------- Pass 2: out = (q_cs @ kv_ext) * norm via MFMA ----------------
__global__ __launch_bounds__(256) void cosformer_out_mfma(
    const float* __restrict__ Q, const __hip_bfloat16* __restrict__ bfrag,
    float* __restrict__ out)
{
    __shared__ __hip_bfloat16 sb[FRAGH];   // 20 KB, fragment-linear
    const int head = blockIdx.x >> 3;
    const int tile = blockIdx.x & 7;
    const int tid  = threadIdx.x;

    {
        const float4* src = (const float4*)(bfrag + (size_t)head * FRAGH);
        float4* dst = (float4*)sb;
        #pragma unroll
        for (int i = 0; i < 5; ++i) dst[tid + 256 * i] = src[tid + 256 * i];
    }

    const int lane = tid & 63;
    const int w    = tid >> 6;
    const int mrow = lane & 15;   // A row within 16-tile; also output col % 16
    const int kgrp = lane >> 4;   // k-chunk of 8 within each 32-k step

    const float* Qb = Q + (size_t)head * SEQ * DIM;
    float*       Ob = out + (size_t)head * SEQ * DIM;
    const int rowblk = tile * 512;

    // prologue: load group-0 Q (16 floats per row-half per lane)
    float4 qb[2][4];
    #pragma unroll
    for (int m = 0; m < 2; ++m) {
        const float4* qr = (const float4*)(Qb + (size_t)(rowblk + w * 32 + m * 16 + mrow) * DIM);
        qb[m][0] = qr[kgrp * 2];
        qb[m][1] = qr[kgrp * 2 + 1];
        qb[m][2] = qr[8 + kgrp * 2];
        qb[m][3] = qr[8 + kgrp * 2 + 1];
    }

    __syncthreads();

    #pragma unroll
    for (int g = 0; g < 4; ++g) {
        const int base = rowblk + (g * 4 + w) * 32;

        // build A fragments: q_cs rows, bf16 (cos and sin halves share Q data)
        bf16x8v af[2][4];
        #pragma unroll
        for (int m = 0; m < 2; ++m) {
            int arow = base + m * 16 + mrow;
            float ang = 1.5707963267948966f * (float)(arow + 1) / (float)SEQ;
            float sn, cn;
            __sincosf(ang, &sn, &cn);
            float crs = cn * 0.125f, srs = sn * 0.125f;
            float lo[8] = {qb[m][0].x, qb[m][0].y, qb[m][0].z, qb[m][0].w,
                           qb[m][1].x, qb[m][1].y, qb[m][1].z, qb[m][1].w};
            float hi[8] = {qb[m][2].x, qb[m][2].y, qb[m][2].z, qb[m][2].w,
                           qb[m][3].x, qb[m][3].y, qb[m][3].z, qb[m][3].w};
            #pragma unroll
            for (int j = 0; j < 8; ++j) {
                float rl = fmaxf(lo[j], 0.f);
                float rh = fmaxf(hi[j], 0.f);
                af[m][0][j] = (__bf16)(rl * crs);
                af[m][1][j] = (__bf16)(rh * crs);
                af[m][2][j] = (__bf16)(rl * srs);
                af[m][3][j] = (__bf16)(rh * srs);
            }
        }

        // prefetch next group's Q; latency hides under MFMA + epilogue
        if (g < 3) {
            #pragma unroll
            for (int m = 0; m < 2; ++m) {
                const float4* qr = (const float4*)(Qb + (size_t)(rowblk + ((g + 1) * 4 + w) * 32 + m * 16 + mrow) * DIM);
                qb[m][0] = qr[kgrp * 2];
                qb[m][1] = qr[kgrp * 2 + 1];
                qb[m][2] = qr[8 + kgrp * 2];
                qb[m][3] = qr[8 + kgrp * 2 + 1];
            }
        }

        f32x4v acc[2][5];
        #pragma unroll
        for (int m = 0; m < 2; ++m)
            #pragma unroll
            for (int t = 0; t < 5; ++t)
                acc[m][t] = (f32x4v){0.f, 0.f, 0.f, 0.f};

        #pragma unroll
        for (int t = 0; t < 5; ++t)
            #pragma unroll
            for (int ks = 0; ks < 4; ++ks) {
                bf16x8v bf = *(const bf16x8v*)&sb[(size_t)(((t * 4 + ks) * 64 + lane) * 8)];
                acc[0][t] = mfma16(af[0][ks], bf, acc[0][t]);
                acc[1][t] = mfma16(af[1][ks], bf, acc[1][t]);
            }

        // epilogue: denominator broadcast (t=4 col 0 lives in lanes l&15==0)
        #pragma unroll
        for (int m = 0; m < 2; ++m) {
            #pragma unroll
            for (int r = 0; r < 4; ++r) {
                float den = __shfl(acc[m][4][r], lane & 48, 64);
                float invd = 1.0f / fmaxf(den, 1e-6f);
                int row = base + m * 16 + kgrp * 4 + r;   // C/D: row=(lane>>4)*4+reg
                float* op = Ob + (size_t)row * DIM + mrow; // col = t*16 + (lane&15)
                op[0]  = acc[m][0][r] * invd;
                op[16] = acc[m][1][r] * invd;
                op[32] = acc[m][2][r] * invd;
                op[48] = acc[m][3][r] * invd;
            }
        }
    }
}

extern "C" void kernel_launch(void* const* d_in, const int* in_sizes, int n_in,
                              void* d_out, int out_size, void* d_ws, size_t ws_size,
                              hipStream_t stream) {
    const float* Q = (const float*)d_in[0];
    const float* K = (const float*)d_in[1];
    const float* V = (const float*)d_in[2];
    float* out = (float*)d_out;
    float* ws  = (float*)d_ws;

    const size_t frag_bytes = (size_t)FRAGH * BHN * sizeof(__hip_bfloat16);
    const size_t need_full  = (size_t)NCHUNK * STRIDE_C * sizeof(float) + frag_bytes;

    if (ws_size >= need_full) {
        float* part = ws;
        __hip_bfloat16* bfrag = (__hip_bfloat16*)(ws + (size_t)NCHUNK * STRIDE_C);
        hipMemsetAsync(bfrag, 0, frag_bytes, stream);
        hipLaunchKernelGGL((cosformer_kv<0>), dim3(BHN * NCHUNK), dim3(256), 0, stream,
                           K, V, part);
        hipLaunchKernelGGL((reduce_pack<NCHUNK>), dim3((int)(STRIDE_C / 256)), dim3(256), 0, stream,
                           part, bfrag);
        hipLaunchKernelGGL(cosformer_out_mfma, dim3(BHN * 8), dim3(256), 0, stream,
                           Q, bfrag, out);
    } else {
        float* part = ws;
        __hip_bfloat16* bfrag = (__hip_bfloat16*)(ws + STRIDE_C);
        hipMemsetAsync(part, 0, STRIDE_C * sizeof(float), stream);
        hipMemsetAsync(bfrag, 0, frag_bytes, stream);
        hipLaunchKernelGGL((cosformer_kv<1>), dim3(BHN * NCHUNK), dim3(256), 0, stream,
                           K, V, part);
        hipLaunchKernelGGL((reduce_pack<1>), dim3((int)(STRIDE_C / 256)), dim3(256), 0, stream,
                           part, bfrag);
        hipLaunchKernelGGL(cosformer_out_mfma, dim3(BHN * 8), dim3(256), 0, stream,
                           Q, bfrag, out);
    }
}

// Round 4
// 80.908 us; speedup vs baseline: 5.2728x; 1.4871x over previous
//
#include <hip/hip_runtime.h>
#include <hip/hip_bf16.h>
#include <math.h>

#define BHN    64
#define SEQ    4096
#define DIM    64
#define NCHUNK 16
#define CHUNK  (SEQ / NCHUNK)        // 256 rows per pass-1 block
#define KSTEP  64                    // s-rows staged per iteration
#define NIT    (CHUNK / KSTEP)       // 4 iterations
#define KVF    (128 * DIM)           // 8192 floats of kv per head
#define STRIDE_C ((size_t)BHN * KVF + (size_t)BHN * 128)   // 532480 floats
#define KSBASE ((size_t)BHN * KVF)   // 524288
#define FRAGH  10240                 // bf16 per head: 5 t * 4 ks * 64 lanes * 8 j
#define LPAD   72                    // LDS row pitch (ushorts): 16B-aligned rows

typedef __bf16 bf16x8v __attribute__((ext_vector_type(8)));
typedef float  f32x4v  __attribute__((ext_vector_type(4)));

__device__ inline f32x4v mfma16(bf16x8v a, bf16x8v b, f32x4v c) {
    return __builtin_amdgcn_mfma_f32_16x16x32_bf16(a, b, c, 0, 0, 0);
}

__device__ inline unsigned pk2(float a, float b) {
    __hip_bfloat162 t(__float2bfloat16(a), __float2bfloat16(b));
    return *(unsigned*)&t;
}

// ------- Pass 1 (MFMA): partial kv/ksum per (head, chunk) -------
// kv[f][m] = sum_s k_cs[s][f] * V[s][m];  ksum[f] via ones-column N-tile.
template<int USE_ATOMIC>
__global__ __launch_bounds__(256) void cosformer_kv_mfma(
    const float* __restrict__ K, const float* __restrict__ V,
    float* __restrict__ part)
{
    __shared__ ushort ktc[64][LPAD];   // relu(K)*cos, transposed [d][s], bf16
    __shared__ ushort kts[64][LPAD];   // relu(K)*sin
    __shared__ ushort vt [64][LPAD];   // V, transposed [m][s], bf16

    const int bh    = blockIdx.x / NCHUNK;
    const int chunk = blockIdx.x % NCHUNK;
    const int row0  = chunk * CHUNK;
    const float* Kb = K + (size_t)bh * SEQ * DIM;
    const float* Vb = V + (size_t)bh * SEQ * DIM;

    const int tid  = threadIdx.x;
    // staging: thread owns s-pair (ssub, ssub+1) x d-block of 8
    const int ssub = (tid & 31) * 2;
    const int dblk = (tid >> 5) * 8;
    // fragments: wave w owns feature-tiles {2w, 2w+1}
    const int lane = tid & 63;
    const int w    = tid >> 6;
    const int frow = lane & 15;
    const int kgrp = lane >> 4;

    f32x4v acc[2][5];
    #pragma unroll
    for (int i = 0; i < 2; ++i)
        #pragma unroll
        for (int t = 0; t < 5; ++t) acc[i][t] = (f32x4v){0.f, 0.f, 0.f, 0.f};

    bf16x8v onef;
    #pragma unroll
    for (int j = 0; j < 8; ++j) onef[j] = (frow == 0) ? (__bf16)1.0f : (__bf16)0.0f;

    float4 kreg[4], vreg[4];   // staged global loads (2 s-rows x 8 floats each)

    auto LOADS = [&](int it) {
        const float* kp = Kb + (size_t)(row0 + it * KSTEP + ssub) * DIM + dblk;
        const float* vp = Vb + (size_t)(row0 + it * KSTEP + ssub) * DIM + dblk;
        kreg[0] = *(const float4*)kp;
        kreg[1] = *(const float4*)(kp + 4);
        kreg[2] = *(const float4*)(kp + DIM);
        kreg[3] = *(const float4*)(kp + DIM + 4);
        vreg[0] = *(const float4*)vp;
        vreg[1] = *(const float4*)(vp + 4);
        vreg[2] = *(const float4*)(vp + DIM);
        vreg[3] = *(const float4*)(vp + DIM + 4);
    };

    auto WRITES = [&](int it) {
        const int l0 = row0 + it * KSTEP + ssub;
        const float CC = 1.5707963267948966f / (float)SEQ;
        float s0v, c0, s1v, c1;
        __sincosf(CC * (float)(l0 + 1), &s0v, &c0);
        __sincosf(CC * (float)(l0 + 2), &s1v, &c1);
        float k0[8] = {kreg[0].x, kreg[0].y, kreg[0].z, kreg[0].w,
                       kreg[1].x, kreg[1].y, kreg[1].z, kreg[1].w};
        float k1[8] = {kreg[2].x, kreg[2].y, kreg[2].z, kreg[2].w,
                       kreg[3].x, kreg[3].y, kreg[3].z, kreg[3].w};
        float v0[8] = {vreg[0].x, vreg[0].y, vreg[0].z, vreg[0].w,
                       vreg[1].x, vreg[1].y, vreg[1].z, vreg[1].w};
        float v1[8] = {vreg[2].x, vreg[2].y, vreg[2].z, vreg[2].w,
                       vreg[3].x, vreg[3].y, vreg[3].z, vreg[3].w};
        #pragma unroll
        for (int i = 0; i < 8; ++i) {
            float r0 = fmaxf(k0[i], 0.f), r1 = fmaxf(k1[i], 0.f);
            *(unsigned*)&ktc[dblk + i][ssub] = pk2(r0 * c0,  r1 * c1);
            *(unsigned*)&kts[dblk + i][ssub] = pk2(r0 * s0v, r1 * s1v);
            *(unsigned*)&vt [dblk + i][ssub] = pk2(v0[i],    v1[i]);
        }
    };

    // prologue
    LOADS(0);
    WRITES(0);
    LOADS(1);
    __syncthreads();

    const ushort (*ap)[LPAD] = (w < 2) ? ktc : kts;
    const int d0 = ((2 * w) & 3) * 16 + frow;   // mi=0 row; mi=1 is d0+16

    for (int it = 0; it < NIT; ++it) {
        #pragma unroll
        for (int ks = 0; ks < 2; ++ks) {
            const int so = ks * 32 + kgrp * 8;
            bf16x8v a0 = *(const bf16x8v*)&ap[d0][so];
            bf16x8v a1 = *(const bf16x8v*)&ap[d0 + 16][so];
            #pragma unroll
            for (int nt = 0; nt < 4; ++nt) {
                bf16x8v b = *(const bf16x8v*)&vt[nt * 16 + frow][so];
                acc[0][nt] = mfma16(a0, b, acc[0][nt]);
                acc[1][nt] = mfma16(a1, b, acc[1][nt]);
            }
            acc[0][4] = mfma16(a0, onef, acc[0][4]);
            acc[1][4] = mfma16(a1, onef, acc[1][4]);
        }
        __syncthreads();          // readers of LDS done
        if (it + 1 < NIT) {
            WRITES(it + 1);       // consumes regs (vmcnt waits here)
            if (it + 2 < NIT) LOADS(it + 2);
            __syncthreads();      // LDS ready for next iteration
        }
    }

    // epilogue: store partials (C/D: col=lane&15, row=(lane>>4)*4+reg)
    if (USE_ATOMIC) {
        float* pb = part + (size_t)bh * KVF;
        float* ps = part + KSBASE + bh * 128;
        #pragma unroll
        for (int mi = 0; mi < 2; ++mi) {
            const int fb = (2 * w + mi) * 16 + kgrp * 4;
            #pragma unroll
            for (int nt = 0; nt < 4; ++nt)
                #pragma unroll
                for (int r = 0; r < 4; ++r)
                    atomicAdd(&pb[(size_t)(fb + r) * DIM + nt * 16 + frow], acc[mi][nt][r]);
            if (frow == 0)
                #pragma unroll
                for (int r = 0; r < 4; ++r) atomicAdd(&ps[fb + r], acc[mi][4][r]);
        }
    } else {
        float* pb = part + STRIDE_C * chunk + (size_t)bh * KVF;
        float* ps = part + STRIDE_C * chunk + KSBASE + bh * 128;
        #pragma unroll
        for (int mi = 0; mi < 2; ++mi) {
            const int fb = (2 * w + mi) * 16 + kgrp * 4;
            #pragma unroll
            for (int nt = 0; nt < 4; ++nt)
                #pragma unroll
                for (int r = 0; r < 4; ++r)
                    pb[(size_t)(fb + r) * DIM + nt * 16 + frow] = acc[mi][nt][r];
            if (frow == 0)
                #pragma unroll
                for (int r = 0; r < 4; ++r) ps[fb + r] = acc[mi][4][r];
        }
    }
}

// ------- Reduce + pack into bf16 B-fragment layout for pass-2 MFMA -------
// bfrag[head][t][ks][lane][j]: B[k][n], k=ks*32+(lane>>4)*8+j, n=t*16+(lane&15)
// t=0..3: kv columns; t=4 col 0: ksum (denominator), other cols zero (memset).
template<int NC>
__global__ __launch_bounds__(256) void reduce_pack(
    const float* __restrict__ part, __hip_bfloat16* __restrict__ bfrag)
{
    size_t o = (size_t)blockIdx.x * 256 + threadIdx.x;
    float s = 0.f;
    #pragma unroll
    for (int c = 0; c < NC; ++c) s += part[(size_t)c * STRIDE_C + o];
    if (o < KSBASE) {
        int head = (int)(o >> 13);
        int r = (int)(o & 8191);
        int k = r >> 6, n = r & 63;
        int t = n >> 4, ks = k >> 5, lg = (k >> 3) & 3, j = k & 7;
        int lane = lg * 16 + (n & 15);
        bfrag[(size_t)head * FRAGH + (size_t)(((t * 4 + ks) * 64 + lane) * 8 + j)] =
            __float2bfloat16(s);
    } else {
        int r = (int)(o - KSBASE);
        int head = r >> 7, k = r & 127;
        int ks = k >> 5, lg = (k >> 3) & 3, j = k & 7;
        bfrag[(size_t)head * FRAGH + (size_t)(((16 + ks) * 64 + lg * 16) * 8 + j)] =
            __float2bfloat16(s);
    }
}

// ---------------- Pass 2: out = (q_cs @ kv_ext) * norm via MFMA ----------------
__global__ __launch_bounds__(256) void cosformer_out_mfma(
    const float* __restrict__ Q, const __hip_bfloat16* __restrict__ bfrag,
    float* __restrict__ out)
{
    __shared__ __hip_bfloat16 sb[FRAGH];   // 20 KB, fragment-linear
    const int head = blockIdx.x >> 3;
    const int tile = blockIdx.x & 7;
    const int tid  = threadIdx.x;

    {
        const float4* src = (const float4*)(bfrag + (size_t)head * FRAGH);
        float4* dst = (float4*)sb;
        #pragma unroll
        for (int i = 0; i < 5; ++i) dst[tid + 256 * i] = src[tid + 256 * i];
    }

    const int lane = tid & 63;
    const int w    = tid >> 6;
    const int mrow = lane & 15;
    const int kgrp = lane >> 4;

    const float* Qb = Q + (size_t)head * SEQ * DIM;
    float*       Ob = out + (size_t)head * SEQ * DIM;
    const int rowblk = tile * 512;

    float4 qb[2][4];
    #pragma unroll
    for (int m = 0; m < 2; ++m) {
        const float4* qr = (const float4*)(Qb + (size_t)(rowblk + w * 32 + m * 16 + mrow) * DIM);
        qb[m][0] = qr[kgrp * 2];
        qb[m][1] = qr[kgrp * 2 + 1];
        qb[m][2] = qr[8 + kgrp * 2];
        qb[m][3] = qr[8 + kgrp * 2 + 1];
    }

    __syncthreads();

    #pragma unroll
    for (int g = 0; g < 4; ++g) {
        const int base = rowblk + (g * 4 + w) * 32;

        bf16x8v af[2][4];
        #pragma unroll
        for (int m = 0; m < 2; ++m) {
            int arow = base + m * 16 + mrow;
            float ang = 1.5707963267948966f * (float)(arow + 1) / (float)SEQ;
            float sn, cn;
            __sincosf(ang, &sn, &cn);
            float crs = cn * 0.125f, srs = sn * 0.125f;
            float lo[8] = {qb[m][0].x, qb[m][0].y, qb[m][0].z, qb[m][0].w,
                           qb[m][1].x, qb[m][1].y, qb[m][1].z, qb[m][1].w};
            float hi[8] = {qb[m][2].x, qb[m][2].y, qb[m][2].z, qb[m][2].w,
                           qb[m][3].x, qb[m][3].y, qb[m][3].z, qb[m][3].w};
            #pragma unroll
            for (int j = 0; j < 8; ++j) {
                float rl = fmaxf(lo[j], 0.f);
                float rh = fmaxf(hi[j], 0.f);
                af[m][0][j] = (__bf16)(rl * crs);
                af[m][1][j] = (__bf16)(rh * crs);
                af[m][2][j] = (__bf16)(rl * srs);
                af[m][3][j] = (__bf16)(rh * srs);
            }
        }

        if (g < 3) {
            #pragma unroll
            for (int m = 0; m < 2; ++m) {
                const float4* qr = (const float4*)(Qb + (size_t)(rowblk + ((g + 1) * 4 + w) * 32 + m * 16 + mrow) * DIM);
                qb[m][0] = qr[kgrp * 2];
                qb[m][1] = qr[kgrp * 2 + 1];
                qb[m][2] = qr[8 + kgrp * 2];
                qb[m][3] = qr[8 + kgrp * 2 + 1];
            }
        }

        f32x4v acc[2][5];
        #pragma unroll
        for (int m = 0; m < 2; ++m)
            #pragma unroll
            for (int t = 0; t < 5; ++t)
                acc[m][t] = (f32x4v){0.f, 0.f, 0.f, 0.f};

        #pragma unroll
        for (int t = 0; t < 5; ++t)
            #pragma unroll
            for (int ks = 0; ks < 4; ++ks) {
                bf16x8v bf = *(const bf16x8v*)&sb[(size_t)(((t * 4 + ks) * 64 + lane) * 8)];
                acc[0][t] = mfma16(af[0][ks], bf, acc[0][t]);
                acc[1][t] = mfma16(af[1][ks], bf, acc[1][t]);
            }

        #pragma unroll
        for (int m = 0; m < 2; ++m) {
            #pragma unroll
            for (int r = 0; r < 4; ++r) {
                float den = __shfl(acc[m][4][r], lane & 48, 64);
                float invd = 1.0f / fmaxf(den, 1e-6f);
                int row = base + m * 16 + kgrp * 4 + r;
                float* op = Ob + (size_t)row * DIM + mrow;
                op[0]  = acc[m][0][r] * invd;
                op[16] = acc[m][1][r] * invd;
                op[32] = acc[m][2][r] * invd;
                op[48] = acc[m][3][r] * invd;
            }
        }
    }
}

extern "C" void kernel_launch(void* const* d_in, const int* in_sizes, int n_in,
                              void* d_out, int out_size, void* d_ws, size_t ws_size,
                              hipStream_t stream) {
    const float* Q = (const float*)d_in[0];
    const float* K = (const float*)d_in[1];
    const float* V = (const float*)d_in[2];
    float* out = (float*)d_out;
    float* ws  = (float*)d_ws;

    const size_t frag_bytes = (size_t)FRAGH * BHN * sizeof(__hip_bfloat16);
    const size_t need_full  = (size_t)NCHUNK * STRIDE_C * sizeof(float) + frag_bytes;

    if (ws_size >= need_full) {
        float* part = ws;
        __hip_bfloat16* bfrag = (__hip_bfloat16*)(ws + (size_t)NCHUNK * STRIDE_C);
        hipMemsetAsync(bfrag, 0, frag_bytes, stream);
        hipLaunchKernelGGL((cosformer_kv_mfma<0>), dim3(BHN * NCHUNK), dim3(256), 0, stream,
                           K, V, part);
        hipLaunchKernelGGL((reduce_pack<NCHUNK>), dim3((int)(STRIDE_C / 256)), dim3(256), 0, stream,
                           part, bfrag);
        hipLaunchKernelGGL(cosformer_out_mfma, dim3(BHN * 8), dim3(256), 0, stream,
                           Q, bfrag, out);
    } else {
        float* part = ws;
        __hip_bfloat16* bfrag = (__hip_bfloat16*)(ws + STRIDE_C);
        hipMemsetAsync(part, 0, STRIDE_C * sizeof(float), stream);
        hipMemsetAsync(bfrag, 0, frag_bytes, stream);
        hipLaunchKernelGGL((cosformer_kv_mfma<1>), dim3(BHN * NCHUNK), dim3(256), 0, stream,
                           K, V, part);
        hipLaunchKernelGGL((reduce_pack<1>), dim3((int)(STRIDE_C / 256)), dim3(256), 0, stream,
                           part, bfrag);
        hipLaunchKernelGGL(cosformer_out_mfma, dim3(BHN * 8), dim3(256), 0, stream,
                           Q, bfrag, out);
    }
}

// Round 5
// 80.145 us; speedup vs baseline: 5.3230x; 1.0095x over previous
//
#include <hip/hip_runtime.h>
#include <hip/hip_bf16.h>
#include <math.h>

#define BHN    64
#define SEQ    4096
#define DIM    64
#define NCHUNK 16
#define CHUNK  (SEQ / NCHUNK)        // 256 rows per pass-1 block
#define KSTEP  64                    // s-rows staged per iteration
#define NIT    (CHUNK / KSTEP)       // 4 iterations
#define KVF    (128 * DIM)           // 8192 floats of kv per head
#define STRIDE_C ((size_t)BHN * KVF + (size_t)BHN * 128)   // 532480 floats
#define KSBASE ((size_t)BHN * KVF)   // 524288
#define FRAGH  10240                 // bf16 per head: 5 t * 4 ks * 64 lanes * 8 j
#define LPAD   72                    // LDS row pitch (ushorts); rows 144B = 16B aligned

typedef __bf16 bf16x8v __attribute__((ext_vector_type(8)));
typedef float  f32x4v  __attribute__((ext_vector_type(4)));

__device__ inline f32x4v mfma16(bf16x8v a, bf16x8v b, f32x4v c) {
    return __builtin_amdgcn_mfma_f32_16x16x32_bf16(a, b, c, 0, 0, 0);
}

__device__ inline unsigned pk2(float a, float b) {
    __hip_bfloat162 t(__float2bfloat16(a), __float2bfloat16(b));
    return *(unsigned*)&t;
}

// XOR swizzle on u32 column index (32 cols of s-pairs per d-row).
// Writes: 2-way bank aliasing (free). b128 reads: uniform 8 lanes/bank.
__device__ inline int swz(int d, int col) { return col ^ (4 * ((d >> 2) & 7)); }

// ------- Pass 1 (MFMA): partial kv/ksum per (head, chunk) -------
// kv[f][m] = sum_s k_cs[s][f] * V[s][m];  ksum[f] via ones-column N-tile.
// 512 threads = 8 waves; wave w owns feature tile w (cos tiles 0-3, sin 4-7).
template<int USE_ATOMIC>
__global__ __launch_bounds__(512) void cosformer_kv_mfma(
    const float* __restrict__ K, const float* __restrict__ V,
    float* __restrict__ part)
{
    __shared__ ushort ktc[64][LPAD];   // relu(K)*cos, transposed [d][s], bf16
    __shared__ ushort kts[64][LPAD];   // relu(K)*sin
    __shared__ ushort vt [64][LPAD];   // V, transposed [m][s], bf16

    const int bh    = blockIdx.x / NCHUNK;
    const int chunk = blockIdx.x % NCHUNK;
    const int row0  = chunk * CHUNK;
    const float* Kb = K + (size_t)bh * SEQ * DIM;
    const float* Vb = V + (size_t)bh * SEQ * DIM;

    const int tid = threadIdx.x;
    // staging: d-fast (coalesced): 16 threads cover one 64-float row
    const int dq = (tid & 15) * 4;   // d-block of 4
    const int g  = tid >> 4;         // s-pair index 0..31 (rows 2g, 2g+1)
    // fragments
    const int lane = tid & 63;
    const int w    = tid >> 6;       // 0..7
    const int frow = lane & 15;
    const int kgrp = lane >> 4;

    f32x4v acc[5];
    #pragma unroll
    for (int t = 0; t < 5; ++t) acc[t] = (f32x4v){0.f, 0.f, 0.f, 0.f};

    bf16x8v onef;
    #pragma unroll
    for (int j = 0; j < 8; ++j) onef[j] = (frow == 0) ? (__bf16)1.0f : (__bf16)0.0f;

    float4 ka, kb2, va, vb2;   // 2 s-rows x 4 d of K and V

    auto LOADS = [&](int it) {
        const float* kp = Kb + (size_t)(row0 + it * KSTEP + 2 * g) * DIM + dq;
        const float* vp = Vb + (size_t)(row0 + it * KSTEP + 2 * g) * DIM + dq;
        ka  = *(const float4*)kp;
        kb2 = *(const float4*)(kp + DIM);
        va  = *(const float4*)vp;
        vb2 = *(const float4*)(vp + DIM);
    };

    auto WRITES = [&](int it) {
        const int l0 = row0 + it * KSTEP + 2 * g;
        const float CC = 1.5707963267948966f / (float)SEQ;
        float s0v, c0, s1v, c1;
        __sincosf(CC * (float)(l0 + 1), &s0v, &c0);
        __sincosf(CC * (float)(l0 + 2), &s1v, &c1);
        float k0[4] = {ka.x, ka.y, ka.z, ka.w};
        float k1[4] = {kb2.x, kb2.y, kb2.z, kb2.w};
        float v0[4] = {va.x, va.y, va.z, va.w};
        float v1[4] = {vb2.x, vb2.y, vb2.z, vb2.w};
        #pragma unroll
        for (int i = 0; i < 4; ++i) {
            const int d = dq + i;
            const int c = swz(d, g);
            float r0 = fmaxf(k0[i], 0.f), r1 = fmaxf(k1[i], 0.f);
            ((unsigned*)&ktc[d][0])[c] = pk2(r0 * c0,  r1 * c1);
            ((unsigned*)&kts[d][0])[c] = pk2(r0 * s0v, r1 * s1v);
            ((unsigned*)&vt [d][0])[c] = pk2(v0[i],    v1[i]);
        }
    };

    // prologue
    LOADS(0);
    WRITES(0);
    LOADS(1);
    __syncthreads();

    const ushort (*ap)[LPAD] = (w < 4) ? ktc : kts;
    const int d0 = (w & 3) * 16 + frow;

    for (int it = 0; it < NIT; ++it) {
        #pragma unroll
        for (int ks = 0; ks < 2; ++ks) {
            const int cb = ks * 16 + kgrp * 4;   // u32 col base (= s-offset/2)
            bf16x8v a = *(const bf16x8v*)&ap[d0][2 * swz(d0, cb)];
            #pragma unroll
            for (int nt = 0; nt < 4; ++nt) {
                const int dn = nt * 16 + frow;
                bf16x8v b = *(const bf16x8v*)&vt[dn][2 * swz(dn, cb)];
                acc[nt] = mfma16(a, b, acc[nt]);
            }
            acc[4] = mfma16(a, onef, acc[4]);
        }
        __syncthreads();          // readers of LDS done
        if (it + 1 < NIT) {
            WRITES(it + 1);       // waits on in-flight loads, converts, writes
            if (it + 2 < NIT) LOADS(it + 2);
            __syncthreads();      // LDS ready for next iteration
        }
    }

    // epilogue (C/D: col=lane&15, row=(lane>>4)*4+reg)
    const int fb = w * 16 + kgrp * 4;
    if (USE_ATOMIC) {
        float* pb = part + (size_t)bh * KVF;
        float* ps = part + KSBASE + bh * 128;
        #pragma unroll
        for (int nt = 0; nt < 4; ++nt)
            #pragma unroll
            for (int r = 0; r < 4; ++r)
                atomicAdd(&pb[(size_t)(fb + r) * DIM + nt * 16 + frow], acc[nt][r]);
        if (frow == 0)
            #pragma unroll
            for (int r = 0; r < 4; ++r) atomicAdd(&ps[fb + r], acc[4][r]);
    } else {
        float* pb = part + STRIDE_C * chunk + (size_t)bh * KVF;
        float* ps = part + STRIDE_C * chunk + KSBASE + bh * 128;
        #pragma unroll
        for (int nt = 0; nt < 4; ++nt)
            #pragma unroll
            for (int r = 0; r < 4; ++r)
                pb[(size_t)(fb + r) * DIM + nt * 16 + frow] = acc[nt][r];
        if (frow == 0)
            #pragma unroll
            for (int r = 0; r < 4; ++r) ps[fb + r] = acc[4][r];
    }
}

// ------- Reduce + pack into bf16 B-fragment layout for pass-2 MFMA -------
// bfrag[head][t][ks][lane][j]: B[k][n], k=ks*32+(lane>>4)*8+j, n=t*16+(lane&15)
// t=0..3: kv columns; t=4 col 0: ksum (denominator), other cols zero (memset).
template<int NC>
__global__ __launch_bounds__(256) void reduce_pack(
    const float* __restrict__ part, __hip_bfloat16* __restrict__ bfrag)
{
    size_t o = (size_t)blockIdx.x * 256 + threadIdx.x;
    float s = 0.f;
    #pragma unroll
    for (int c = 0; c < NC; ++c) s += part[(size_t)c * STRIDE_C + o];
    if (o < KSBASE) {
        int head = (int)(o >> 13);
        int r = (int)(o & 8191);
        int k = r >> 6, n = r & 63;
        int t = n >> 4, ks = k >> 5, lg = (k >> 3) & 3, j = k & 7;
        int lane = lg * 16 + (n & 15);
        bfrag[(size_t)head * FRAGH + (size_t)(((t * 4 + ks) * 64 + lane) * 8 + j)] =
            __float2bfloat16(s);
    } else {
        int r = (int)(o - KSBASE);
        int head = r >> 7, k = r & 127;
        int ks = k >> 5, lg = (k >> 3) & 3, j = k & 7;
        bfrag[(size_t)head * FRAGH + (size_t)(((16 + ks) * 64 + lg * 16) * 8 + j)] =
            __float2bfloat16(s);
    }
}

// ---------------- Pass 2: out = (q_cs @ kv_ext) * norm via MFMA ----------------
__global__ __launch_bounds__(256) void cosformer_out_mfma(
    const float* __restrict__ Q, const __hip_bfloat16* __restrict__ bfrag,
    float* __restrict__ out)
{
    __shared__ __hip_bfloat16 sb[FRAGH];   // 20 KB, fragment-linear
    const int head = blockIdx.x >> 3;
    const int tile = blockIdx.x & 7;
    const int tid  = threadIdx.x;

    {
        const float4* src = (const float4*)(bfrag + (size_t)head * FRAGH);
        float4* dst = (float4*)sb;
        #pragma unroll
        for (int i = 0; i < 5; ++i) dst[tid + 256 * i] = src[tid + 256 * i];
    }

    const int lane = tid & 63;
    const int w    = tid >> 6;
    const int mrow = lane & 15;
    const int kgrp = lane >> 4;

    const float* Qb = Q + (size_t)head * SEQ * DIM;
    float*       Ob = out + (size_t)head * SEQ * DIM;
    const int rowblk = tile * 512;

    float4 qb[2][4];
    #pragma unroll
    for (int m = 0; m < 2; ++m) {
        const float4* qr = (const float4*)(Qb + (size_t)(rowblk + w * 32 + m * 16 + mrow) * DIM);
        qb[m][0] = qr[kgrp * 2];
        qb[m][1] = qr[kgrp * 2 + 1];
        qb[m][2] = qr[8 + kgrp * 2];
        qb[m][3] = qr[8 + kgrp * 2 + 1];
    }

    __syncthreads();

    #pragma unroll
    for (int g = 0; g < 4; ++g) {
        const int base = rowblk + (g * 4 + w) * 32;

        bf16x8v af[2][4];
        #pragma unroll
        for (int m = 0; m < 2; ++m) {
            int arow = base + m * 16 + mrow;
            float ang = 1.5707963267948966f * (float)(arow + 1) / (float)SEQ;
            float sn, cn;
            __sincosf(ang, &sn, &cn);
            float crs = cn * 0.125f, srs = sn * 0.125f;
            float lo[8] = {qb[m][0].x, qb[m][0].y, qb[m][0].z, qb[m][0].w,
                           qb[m][1].x, qb[m][1].y, qb[m][1].z, qb[m][1].w};
            float hi[8] = {qb[m][2].x, qb[m][2].y, qb[m][2].z, qb[m][2].w,
                           qb[m][3].x, qb[m][3].y, qb[m][3].z, qb[m][3].w};
            #pragma unroll
            for (int j = 0; j < 8; ++j) {
                float rl = fmaxf(lo[j], 0.f);
                float rh = fmaxf(hi[j], 0.f);
                af[m][0][j] = (__bf16)(rl * crs);
                af[m][1][j] = (__bf16)(rh * crs);
                af[m][2][j] = (__bf16)(rl * srs);
                af[m][3][j] = (__bf16)(rh * srs);
            }
        }

        if (g < 3) {
            #pragma unroll
            for (int m = 0; m < 2; ++m) {
                const float4* qr = (const float4*)(Qb + (size_t)(rowblk + ((g + 1) * 4 + w) * 32 + m * 16 + mrow) * DIM);
                qb[m][0] = qr[kgrp * 2];
                qb[m][1] = qr[kgrp * 2 + 1];
                qb[m][2] = qr[8 + kgrp * 2];
                qb[m][3] = qr[8 + kgrp * 2 + 1];
            }
        }

        f32x4v acc[2][5];
        #pragma unroll
        for (int m = 0; m < 2; ++m)
            #pragma unroll
            for (int t = 0; t < 5; ++t)
                acc[m][t] = (f32x4v){0.f, 0.f, 0.f, 0.f};

        #pragma unroll
        for (int t = 0; t < 5; ++t)
            #pragma unroll
            for (int ks = 0; ks < 4; ++ks) {
                bf16x8v bf = *(const bf16x8v*)&sb[(size_t)(((t * 4 + ks) * 64 + lane) * 8)];
                acc[0][t] = mfma16(af[0][ks], bf, acc[0][t]);
                acc[1][t] = mfma16(af[1][ks], bf, acc[1][t]);
            }

        #pragma unroll
        for (int m = 0; m < 2; ++m) {
            #pragma unroll
            for (int r = 0; r < 4; ++r) {
                float den = __shfl(acc[m][4][r], lane & 48, 64);
                float invd = 1.0f / fmaxf(den, 1e-6f);
                int row = base + m * 16 + kgrp * 4 + r;
                float* op = Ob + (size_t)row * DIM + mrow;
                op[0]  = acc[m][0][r] * invd;
                op[16] = acc[m][1][r] * invd;
                op[32] = acc[m][2][r] * invd;
                op[48] = acc[m][3][r] * invd;
            }
        }
    }
}

extern "C" void kernel_launch(void* const* d_in, const int* in_sizes, int n_in,
                              void* d_out, int out_size, void* d_ws, size_t ws_size,
                              hipStream_t stream) {
    const float* Q = (const float*)d_in[0];
    const float* K = (const float*)d_in[1];
    const float* V = (const float*)d_in[2];
    float* out = (float*)d_out;
    float* ws  = (float*)d_ws;

    const size_t frag_bytes = (size_t)FRAGH * BHN * sizeof(__hip_bfloat16);
    const size_t need_full  = (size_t)NCHUNK * STRIDE_C * sizeof(float) + frag_bytes;

    if (ws_size >= need_full) {
        float* part = ws;
        __hip_bfloat16* bfrag = (__hip_bfloat16*)(ws + (size_t)NCHUNK * STRIDE_C);
        hipMemsetAsync(bfrag, 0, frag_bytes, stream);
        hipLaunchKernelGGL((cosformer_kv_mfma<0>), dim3(BHN * NCHUNK), dim3(512), 0, stream,
                           K, V, part);
        hipLaunchKernelGGL((reduce_pack<NCHUNK>), dim3((int)(STRIDE_C / 256)), dim3(256), 0, stream,
                           part, bfrag);
        hipLaunchKernelGGL(cosformer_out_mfma, dim3(BHN * 8), dim3(256), 0, stream,
                           Q, bfrag, out);
    } else {
        float* part = ws;
        __hip_bfloat16* bfrag = (__hip_bfloat16*)(ws + STRIDE_C);
        hipMemsetAsync(part, 0, STRIDE_C * sizeof(float), stream);
        hipMemsetAsync(bfrag, 0, frag_bytes, stream);
        hipLaunchKernelGGL((cosformer_kv_mfma<1>), dim3(BHN * NCHUNK), dim3(512), 0, stream,
                           K, V, part);
        hipLaunchKernelGGL((reduce_pack<1>), dim3((int)(STRIDE_C / 256)), dim3(256), 0, stream,
                           part, bfrag);
        hipLaunchKernelGGL(cosformer_out_mfma, dim3(BHN * 8), dim3(256), 0, stream,
                           Q, bfrag, out);
    }
}

// Round 6
// 79.221 us; speedup vs baseline: 5.3851x; 1.0117x over previous
//
#include <hip/hip_runtime.h>
#include <hip/hip_bf16.h>
#include <math.h>

#define BHN    64
#define SEQ    4096
#define DIM    64
#define NCHUNK 16
#define CHUNK  (SEQ / NCHUNK)        // 256 rows per pass-1 block
#define KSTEP  64                    // s-rows staged per iteration
#define NIT    (CHUNK / KSTEP)       // 4 iterations
#define KVF    (128 * DIM)           // 8192 floats of kv per head
#define STRIDE_C ((size_t)BHN * KVF + (size_t)BHN * 128)   // 532480 floats
#define KSBASE ((size_t)BHN * KVF)   // 524288
#define FRAGH  10240                 // bf16 per head: 5 t * 4 ks * 64 lanes * 8 j
#define LPAD   72                    // LDS row pitch (ushorts); rows 144B = 16B aligned

typedef __bf16 bf16x8v __attribute__((ext_vector_type(8)));
typedef float  f32x4v  __attribute__((ext_vector_type(4)));

__device__ inline f32x4v mfma16(bf16x8v a, bf16x8v b, f32x4v c) {
    return __builtin_amdgcn_mfma_f32_16x16x32_bf16(a, b, c, 0, 0, 0);
}

__device__ inline unsigned pk2(float a, float b) {
    __hip_bfloat162 t(__float2bfloat16(a), __float2bfloat16(b));
    return *(unsigned*)&t;
}

// XOR swizzle on u32 column index (32 cols of s-pairs per d-row).
__device__ inline int swz(int d, int col) { return col ^ (4 * ((d >> 2) & 7)); }

// ------- Pass 1 (MFMA): partial kv/ksum per (head, chunk) -------
// kv[f][m] = sum_s k_cs[s][f] * V[s][m];  ksum[f] via ones-column N-tile.
// 512 threads = 8 waves; wave w owns feature tile w (cos tiles 0-3, sin 4-7).
// Deep pipeline: 2 register staging sets; every vmcnt wait covered by >=1 iter.
template<int USE_ATOMIC>
__global__ __launch_bounds__(512) void cosformer_kv_mfma(
    const float* __restrict__ K, const float* __restrict__ V,
    float* __restrict__ part)
{
    __shared__ ushort ktc[64][LPAD];   // relu(K)*cos, transposed [d][s], bf16
    __shared__ ushort kts[64][LPAD];   // relu(K)*sin
    __shared__ ushort vt [64][LPAD];   // V, transposed [m][s], bf16

    const int bh    = blockIdx.x / NCHUNK;
    const int chunk = blockIdx.x % NCHUNK;
    const int row0  = chunk * CHUNK;
    const float* Kb = K + (size_t)bh * SEQ * DIM;
    const float* Vb = V + (size_t)bh * SEQ * DIM;

    const int tid = threadIdx.x;
    // staging: d-fast (coalesced): 16 threads cover one 64-float row
    const int dq = (tid & 15) * 4;   // d-block of 4
    const int g  = tid >> 4;         // s-pair index 0..31 (rows 2g, 2g+1)
    // fragments
    const int lane = tid & 63;
    const int w    = tid >> 6;       // 0..7
    const int frow = lane & 15;
    const int kgrp = lane >> 4;

    f32x4v acc[5];
    #pragma unroll
    for (int t = 0; t < 5; ++t) acc[t] = (f32x4v){0.f, 0.f, 0.f, 0.f};

    bf16x8v onef;
    #pragma unroll
    for (int j = 0; j < 8; ++j) onef[j] = (frow == 0) ? (__bf16)1.0f : (__bf16)0.0f;

    // two register staging sets: r[0]=K row a, r[1]=K row b, r[2]=V a, r[3]=V b
    float4 s0[4], s1[4];

    auto LOADS = [&](int it, float4* r) {
        const float* kp = Kb + (size_t)(row0 + it * KSTEP + 2 * g) * DIM + dq;
        const float* vp = Vb + (size_t)(row0 + it * KSTEP + 2 * g) * DIM + dq;
        r[0] = *(const float4*)kp;
        r[1] = *(const float4*)(kp + DIM);
        r[2] = *(const float4*)vp;
        r[3] = *(const float4*)(vp + DIM);
    };

    auto WRITES = [&](int it, const float4* r) {
        const int l0 = row0 + it * KSTEP + 2 * g;
        const float CC = 1.5707963267948966f / (float)SEQ;
        float s0v, c0, s1v, c1;
        __sincosf(CC * (float)(l0 + 1), &s0v, &c0);
        __sincosf(CC * (float)(l0 + 2), &s1v, &c1);
        float k0[4] = {r[0].x, r[0].y, r[0].z, r[0].w};
        float k1[4] = {r[1].x, r[1].y, r[1].z, r[1].w};
        float v0[4] = {r[2].x, r[2].y, r[2].z, r[2].w};
        float v1[4] = {r[3].x, r[3].y, r[3].z, r[3].w};
        #pragma unroll
        for (int i = 0; i < 4; ++i) {
            const int d = dq + i;
            const int c = swz(d, g);
            float r0 = fmaxf(k0[i], 0.f), r1 = fmaxf(k1[i], 0.f);
            ((unsigned*)&ktc[d][0])[c] = pk2(r0 * c0,  r1 * c1);
            ((unsigned*)&kts[d][0])[c] = pk2(r0 * s0v, r1 * s1v);
            ((unsigned*)&vt [d][0])[c] = pk2(v0[i],    v1[i]);
        }
    };

    // prologue: L0->s0, L1->s1 both in flight; W0 eats the one cold stall
    // while L1 (and then L2) fly; L2 reuses s0 after W0 consumed it.
    LOADS(0, s0);
    LOADS(1, s1);
    WRITES(0, s0);
    LOADS(2, s0);
    __syncthreads();

    const ushort (*ap)[LPAD] = (w < 4) ? ktc : kts;
    const int d0 = (w & 3) * 16 + frow;

    #pragma unroll
    for (int it = 0; it < NIT; ++it) {
        #pragma unroll
        for (int ks = 0; ks < 2; ++ks) {
            const int cb = ks * 16 + kgrp * 4;   // u32 col base (= s-offset/2)
            bf16x8v a = *(const bf16x8v*)&ap[d0][2 * swz(d0, cb)];
            #pragma unroll
            for (int nt = 0; nt < 4; ++nt) {
                const int dn = nt * 16 + frow;
                bf16x8v b = *(const bf16x8v*)&vt[dn][2 * swz(dn, cb)];
                acc[nt] = mfma16(a, b, acc[nt]);
            }
            acc[4] = mfma16(a, onef, acc[4]);
        }
        __syncthreads();          // readers of LDS done
        if (it + 1 < NIT) {
            // stage (it+1): its loads were issued >=1 full iteration ago;
            // the other set's loads remain in flight across the wait.
            WRITES(it + 1, ((it + 1) & 1) ? s1 : s0);
            if (it + 3 < NIT) LOADS(it + 3, ((it + 3) & 1) ? s1 : s0);
            __syncthreads();      // LDS ready for next iteration
        }
    }

    // epilogue (C/D: col=lane&15, row=(lane>>4)*4+reg)
    const int fb = w * 16 + kgrp * 4;
    if (USE_ATOMIC) {
        float* pb = part + (size_t)bh * KVF;
        float* ps = part + KSBASE + bh * 128;
        #pragma unroll
        for (int nt = 0; nt < 4; ++nt)
            #pragma unroll
            for (int r = 0; r < 4; ++r)
                atomicAdd(&pb[(size_t)(fb + r) * DIM + nt * 16 + frow], acc[nt][r]);
        if (frow == 0)
            #pragma unroll
            for (int r = 0; r < 4; ++r) atomicAdd(&ps[fb + r], acc[4][r]);
    } else {
        float* pb = part + STRIDE_C * chunk + (size_t)bh * KVF;
        float* ps = part + STRIDE_C * chunk + KSBASE + bh * 128;
        #pragma unroll
        for (int nt = 0; nt < 4; ++nt)
            #pragma unroll
            for (int r = 0; r < 4; ++r)
                pb[(size_t)(fb + r) * DIM + nt * 16 + frow] = acc[nt][r];
        if (frow == 0)
            #pragma unroll
            for (int r = 0; r < 4; ++r) ps[fb + r] = acc[4][r];
    }
}

// ------- Reduce + pack into bf16 B-fragment layout for pass-2 MFMA -------
// bfrag[head][t][ks][lane][j]: B[k][n], k=ks*32+(lane>>4)*8+j, n=t*16+(lane&15)
// t=0..3: kv columns; t=4 col 0: ksum (denominator), other cols zero (memset).
template<int NC>
__global__ __launch_bounds__(256) void reduce_pack(
    const float* __restrict__ part, __hip_bfloat16* __restrict__ bfrag)
{
    size_t o = (size_t)blockIdx.x * 256 + threadIdx.x;
    float s = 0.f;
    #pragma unroll
    for (int c = 0; c < NC; ++c) s += part[(size_t)c * STRIDE_C + o];
    if (o < KSBASE) {
        int head = (int)(o >> 13);
        int r = (int)(o & 8191);
        int k = r >> 6, n = r & 63;
        int t = n >> 4, ks = k >> 5, lg = (k >> 3) & 3, j = k & 7;
        int lane = lg * 16 + (n & 15);
        bfrag[(size_t)head * FRAGH + (size_t)(((t * 4 + ks) * 64 + lane) * 8 + j)] =
            __float2bfloat16(s);
    } else {
        int r = (int)(o - KSBASE);
        int head = r >> 7, k = r & 127;
        int ks = k >> 5, lg = (k >> 3) & 3, j = k & 7;
        bfrag[(size_t)head * FRAGH + (size_t)(((16 + ks) * 64 + lg * 16) * 8 + j)] =
            __float2bfloat16(s);
    }
}

// ---------------- Pass 2: out = (q_cs @ kv_ext) * norm via MFMA ----------------
__global__ __launch_bounds__(256) void cosformer_out_mfma(
    const float* __restrict__ Q, const __hip_bfloat16* __restrict__ bfrag,
    float* __restrict__ out)
{
    __shared__ __hip_bfloat16 sb[FRAGH];   // 20 KB, fragment-linear
    const int head = blockIdx.x >> 3;
    const int tile = blockIdx.x & 7;
    const int tid  = threadIdx.x;

    {
        const float4* src = (const float4*)(bfrag + (size_t)head * FRAGH);
        float4* dst = (float4*)sb;
        #pragma unroll
        for (int i = 0; i < 5; ++i) dst[tid + 256 * i] = src[tid + 256 * i];
    }

    const int lane = tid & 63;
    const int w    = tid >> 6;
    const int mrow = lane & 15;
    const int kgrp = lane >> 4;

    const float* Qb = Q + (size_t)head * SEQ * DIM;
    float*       Ob = out + (size_t)head * SEQ * DIM;
    const int rowblk = tile * 512;

    float4 qb[2][4];
    #pragma unroll
    for (int m = 0; m < 2; ++m) {
        const float4* qr = (const float4*)(Qb + (size_t)(rowblk + w * 32 + m * 16 + mrow) * DIM);
        qb[m][0] = qr[kgrp * 2];
        qb[m][1] = qr[kgrp * 2 + 1];
        qb[m][2] = qr[8 + kgrp * 2];
        qb[m][3] = qr[8 + kgrp * 2 + 1];
    }

    __syncthreads();

    #pragma unroll
    for (int g = 0; g < 4; ++g) {
        const int base = rowblk + (g * 4 + w) * 32;

        bf16x8v af[2][4];
        #pragma unroll
        for (int m = 0; m < 2; ++m) {
            int arow = base + m * 16 + mrow;
            float ang = 1.5707963267948966f * (float)(arow + 1) / (float)SEQ;
            float sn, cn;
            __sincosf(ang, &sn, &cn);
            float crs = cn * 0.125f, srs = sn * 0.125f;
            float lo[8] = {qb[m][0].x, qb[m][0].y, qb[m][0].z, qb[m][0].w,
                           qb[m][1].x, qb[m][1].y, qb[m][1].z, qb[m][1].w};
            float hi[8] = {qb[m][2].x, qb[m][2].y, qb[m][2].z, qb[m][2].w,
                           qb[m][3].x, qb[m][3].y, qb[m][3].z, qb[m][3].w};
            #pragma unroll
            for (int j = 0; j < 8; ++j) {
                float rl = fmaxf(lo[j], 0.f);
                float rh = fmaxf(hi[j], 0.f);
                af[m][0][j] = (__bf16)(rl * crs);
                af[m][1][j] = (__bf16)(rh * crs);
                af[m][2][j] = (__bf16)(rl * srs);
                af[m][3][j] = (__bf16)(rh * srs);
            }
        }

        if (g < 3) {
            #pragma unroll
            for (int m = 0; m < 2; ++m) {
                const float4* qr = (const float4*)(Qb + (size_t)(rowblk + ((g + 1) * 4 + w) * 32 + m * 16 + mrow) * DIM);
                qb[m][0] = qr[kgrp * 2];
                qb[m][1] = qr[kgrp * 2 + 1];
                qb[m][2] = qr[8 + kgrp * 2];
                qb[m][3] = qr[8 + kgrp * 2 + 1];
            }
        }

        f32x4v acc[2][5];
        #pragma unroll
        for (int m = 0; m < 2; ++m)
            #pragma unroll
            for (int t = 0; t < 5; ++t)
                acc[m][t] = (f32x4v){0.f, 0.f, 0.f, 0.f};

        #pragma unroll
        for (int t = 0; t < 5; ++t)
            #pragma unroll
            for (int ks = 0; ks < 4; ++ks) {
                bf16x8v bf = *(const bf16x8v*)&sb[(size_t)(((t * 4 + ks) * 64 + lane) * 8)];
                acc[0][t] = mfma16(af[0][ks], bf, acc[0][t]);
                acc[1][t] = mfma16(af[1][ks], bf, acc[1][t]);
            }

        #pragma unroll
        for (int m = 0; m < 2; ++m) {
            #pragma unroll
            for (int r = 0; r < 4; ++r) {
                float den = __shfl(acc[m][4][r], lane & 48, 64);
                float invd = 1.0f / fmaxf(den, 1e-6f);
                int row = base + m * 16 + kgrp * 4 + r;
                float* op = Ob + (size_t)row * DIM + mrow;
                op[0]  = acc[m][0][r] * invd;
                op[16] = acc[m][1][r] * invd;
                op[32] = acc[m][2][r] * invd;
                op[48] = acc[m][3][r] * invd;
            }
        }
    }
}

extern "C" void kernel_launch(void* const* d_in, const int* in_sizes, int n_in,
                              void* d_out, int out_size, void* d_ws, size_t ws_size,
                              hipStream_t stream) {
    const float* Q = (const float*)d_in[0];
    const float* K = (const float*)d_in[1];
    const float* V = (const float*)d_in[2];
    float* out = (float*)d_out;
    float* ws  = (float*)d_ws;

    const size_t frag_bytes = (size_t)FRAGH * BHN * sizeof(__hip_bfloat16);
    const size_t need_full  = (size_t)NCHUNK * STRIDE_C * sizeof(float) + frag_bytes;

    if (ws_size >= need_full) {
        float* part = ws;
        __hip_bfloat16* bfrag = (__hip_bfloat16*)(ws + (size_t)NCHUNK * STRIDE_C);
        hipMemsetAsync(bfrag, 0, frag_bytes, stream);
        hipLaunchKernelGGL((cosformer_kv_mfma<0>), dim3(BHN * NCHUNK), dim3(512), 0, stream,
                           K, V, part);
        hipLaunchKernelGGL((reduce_pack<NCHUNK>), dim3((int)(STRIDE_C / 256)), dim3(256), 0, stream,
                           part, bfrag);
        hipLaunchKernelGGL(cosformer_out_mfma, dim3(BHN * 8), dim3(256), 0, stream,
                           Q, bfrag, out);
    } else {
        float* part = ws;
        __hip_bfloat16* bfrag = (__hip_bfloat16*)(ws + STRIDE_C);
        hipMemsetAsync(part, 0, STRIDE_C * sizeof(float), stream);
        hipMemsetAsync(bfrag, 0, frag_bytes, stream);
        hipLaunchKernelGGL((cosformer_kv_mfma<1>), dim3(BHN * NCHUNK), dim3(512), 0, stream,
                           K, V, part);
        hipLaunchKernelGGL((reduce_pack<1>), dim3((int)(STRIDE_C / 256)), dim3(256), 0, stream,
                           part, bfrag);
        hipLaunchKernelGGL(cosformer_out_mfma, dim3(BHN * 8), dim3(256), 0, stream,
                           Q, bfrag, out);
    }
}

// Round 8
// 70.043 us; speedup vs baseline: 6.0906x; 1.1310x over previous
//
#include <hip/hip_runtime.h>
#include <hip/hip_bf16.h>
#include <math.h>

#define BHN    64
#define SEQ    4096
#define DIM    64
#define NCHUNK 8
#define CHUNK  (SEQ / NCHUNK)        // 512 rows per pass-1 block
#define KSTEP  64                    // s-rows staged per iteration
#define NIT    (CHUNK / KSTEP)       // 8 iterations
#define KVF    (128 * DIM)           // 8192 floats of kv per head
#define STRIDE_C ((size_t)BHN * KVF + (size_t)BHN * 128)   // 532480 floats
#define KSBASE ((size_t)BHN * KVF)   // 524288
#define FRAGH  10240                 // bf16 per head: 5 t * 4 ks * 64 lanes * 8 j
#define LPAD   72                    // LDS row pitch (ushorts); rows 144B = 16B aligned

typedef __bf16 bf16x8v __attribute__((ext_vector_type(8)));
typedef float  f32x4v  __attribute__((ext_vector_type(4)));

__device__ inline f32x4v mfma16(bf16x8v a, bf16x8v b, f32x4v c) {
    return __builtin_amdgcn_mfma_f32_16x16x32_bf16(a, b, c, 0, 0, 0);
}

__device__ inline unsigned pk2(float a, float b) {
    __hip_bfloat162 t(__float2bfloat16(a), __float2bfloat16(b));
    return *(unsigned*)&t;
}

// XOR swizzle on u32 column index (32 cols of s-pairs per d-row).
__device__ inline int swz(int d, int col) { return col ^ (4 * ((d >> 2) & 7)); }

// ------- Pass 1 (MFMA): partial kv/ksum per (head, chunk) -------
// kv[f][m] = sum_s k_cs[s][f] * V[s][m];  ksum[f] via ones-column N-tile.
// 512 threads = 8 waves; wave w owns feature tile w (cos tiles 0-3, sin 4-7).
// NIT=8 iterations; LDS double-buffer (1 barrier/iter); 3 register load sets.
// Load schedule: prologue L0,L1,L2, W0, L3; loop it issues L(it+4).
// Consumption: W(t) uses set t%3; W(t)'s loads are issued >=1 iter earlier.
template<int USE_ATOMIC>
__global__ __launch_bounds__(512) void cosformer_kv_mfma(
    const float* __restrict__ K, const float* __restrict__ V,
    float* __restrict__ part)
{
    __shared__ ushort ktc[2][64][LPAD];   // relu(K)*cos, transposed [d][s], bf16
    __shared__ ushort kts[2][64][LPAD];   // relu(K)*sin
    __shared__ ushort vtt[2][64][LPAD];   // V, transposed [m][s], bf16

    const int bh    = blockIdx.x / NCHUNK;
    const int chunk = blockIdx.x % NCHUNK;
    const int row0  = chunk * CHUNK;
    const float* Kb = K + (size_t)bh * SEQ * DIM;
    const float* Vb = V + (size_t)bh * SEQ * DIM;

    const int tid = threadIdx.x;
    // staging: d-fast (coalesced): 16 threads cover one 64-float row
    const int dq = (tid & 15) * 4;   // d-block of 4
    const int g  = tid >> 4;         // s-pair index 0..31 (rows 2g, 2g+1)
    // fragments
    const int lane = tid & 63;
    const int w    = tid >> 6;       // 0..7
    const int frow = lane & 15;
    const int kgrp = lane >> 4;

    f32x4v acc[5];
    #pragma unroll
    for (int t = 0; t < 5; ++t) acc[t] = (f32x4v){0.f, 0.f, 0.f, 0.f};

    bf16x8v onef;
    #pragma unroll
    for (int j = 0; j < 8; ++j) onef[j] = (frow == 0) ? (__bf16)1.0f : (__bf16)0.0f;

    // three register staging sets (16 VGPR each)
    float4 sA[4], sB[4], sC[4];

    auto LOADS = [&](int it, float4* r) {
        const float* kp = Kb + (size_t)(row0 + it * KSTEP + 2 * g) * DIM + dq;
        const float* vp = Vb + (size_t)(row0 + it * KSTEP + 2 * g) * DIM + dq;
        r[0] = *(const float4*)kp;
        r[1] = *(const float4*)(kp + DIM);
        r[2] = *(const float4*)vp;
        r[3] = *(const float4*)(vp + DIM);
    };

    auto WRITES = [&](int it, const float4* r, int buf) {
        const int l0 = row0 + it * KSTEP + 2 * g;
        const float CC = 1.5707963267948966f / (float)SEQ;
        float s0v, c0, s1v, c1;
        __sincosf(CC * (float)(l0 + 1), &s0v, &c0);
        __sincosf(CC * (float)(l0 + 2), &s1v, &c1);
        float k0[4] = {r[0].x, r[0].y, r[0].z, r[0].w};
        float k1[4] = {r[1].x, r[1].y, r[1].z, r[1].w};
        float v0[4] = {r[2].x, r[2].y, r[2].z, r[2].w};
        float v1[4] = {r[3].x, r[3].y, r[3].z, r[3].w};
        #pragma unroll
        for (int i = 0; i < 4; ++i) {
            const int d = dq + i;
            const int c = swz(d, g);
            float r0 = fmaxf(k0[i], 0.f), r1 = fmaxf(k1[i], 0.f);
            ((unsigned*)&ktc[buf][d][0])[c] = pk2(r0 * c0,  r1 * c1);
            ((unsigned*)&kts[buf][d][0])[c] = pk2(r0 * s0v, r1 * s1v);
            ((unsigned*)&vtt[buf][d][0])[c] = pk2(v0[i],    v1[i]);
        }
    };

    // set index for load/stage i is i%3 (A,B,C rotating)
    auto LOADS_SEL = [&](int it) {
        int sel = it % 3;
        if (sel == 0) LOADS(it, sA);
        else if (sel == 1) LOADS(it, sB);
        else LOADS(it, sC);
    };
    auto WRITES_SEL = [&](int it, int buf) {
        int sel = it % 3;
        if (sel == 0) WRITES(it, sA, buf);
        else if (sel == 1) WRITES(it, sB, buf);
        else WRITES(it, sC, buf);
    };

    // prologue: one cold stall (W0 waits on L0) while L1,L2 fly;
    // set A is freed by W0 and immediately reloaded with tile 3.
    LOADS_SEL(0);
    LOADS_SEL(1);
    LOADS_SEL(2);
    WRITES_SEL(0, 0);
    LOADS_SEL(3);
    __syncthreads();

    const int d0 = (w & 3) * 16 + frow;

    #pragma unroll
    for (int it = 0; it < NIT; ++it) {
        const int buf = it & 1;
        const ushort (*ap)[LPAD] = (w < 4) ? ktc[buf] : kts[buf];
        const ushort (*bp)[LPAD] = vtt[buf];
        #pragma unroll
        for (int ks = 0; ks < 2; ++ks) {
            const int cb = ks * 16 + kgrp * 4;   // u32 col base (= s-offset/2)
            bf16x8v a = *(const bf16x8v*)&ap[d0][2 * swz(d0, cb)];
            #pragma unroll
            for (int nt = 0; nt < 4; ++nt) {
                const int dn = nt * 16 + frow;
                bf16x8v b = *(const bf16x8v*)&bp[dn][2 * swz(dn, cb)];
                acc[nt] = mfma16(a, b, acc[nt]);
            }
            acc[4] = mfma16(a, onef, acc[4]);
        }
        if (it + 1 < NIT) {
            // stage next tile into the other LDS buffer; its loads were
            // issued >=1 full iteration ago; then refill the freed set.
            WRITES_SEL(it + 1, buf ^ 1);
            if (it + 4 < NIT) LOADS_SEL(it + 4);
        }
        __syncthreads();   // next buffer staged; readers of buf done
    }

    // epilogue (C/D: col=lane&15, row=(lane>>4)*4+reg)
    const int fb = w * 16 + kgrp * 4;
    if (USE_ATOMIC) {
        float* pb = part + (size_t)bh * KVF;
        float* ps = part + KSBASE + bh * 128;
        #pragma unroll
        for (int nt = 0; nt < 4; ++nt)
            #pragma unroll
            for (int r = 0; r < 4; ++r)
                atomicAdd(&pb[(size_t)(fb + r) * DIM + nt * 16 + frow], acc[nt][r]);
        if (frow == 0)
            #pragma unroll
            for (int r = 0; r < 4; ++r) atomicAdd(&ps[fb + r], acc[4][r]);
    } else {
        float* pb = part + STRIDE_C * chunk + (size_t)bh * KVF;
        float* ps = part + STRIDE_C * chunk + KSBASE + bh * 128;
        #pragma unroll
        for (int nt = 0; nt < 4; ++nt)
            #pragma unroll
            for (int r = 0; r < 4; ++r)
                pb[(size_t)(fb + r) * DIM + nt * 16 + frow] = acc[nt][r];
        if (frow == 0)
            #pragma unroll
            for (int r = 0; r < 4; ++r) ps[fb + r] = acc[4][r];
    }
}

// ------- Reduce + pack into bf16 B-fragment layout for pass-2 MFMA -------
// bfrag[head][t][ks][lane][j]: B[k][n], k=ks*32+(lane>>4)*8+j, n=t*16+(lane&15)
// t=0..3: kv columns; t=4 col 0: ksum (denominator), other cols zero (memset).
template<int NC>
__global__ __launch_bounds__(256) void reduce_pack(
    const float* __restrict__ part, __hip_bfloat16* __restrict__ bfrag)
{
    size_t o = (size_t)blockIdx.x * 256 + threadIdx.x;
    float s = 0.f;
    #pragma unroll
    for (int c = 0; c < NC; ++c) s += part[(size_t)c * STRIDE_C + o];
    if (o < KSBASE) {
        int head = (int)(o >> 13);
        int r = (int)(o & 8191);
        int k = r >> 6, n = r & 63;
        int t = n >> 4, ks = k >> 5, lg = (k >> 3) & 3, j = k & 7;
        int lane = lg * 16 + (n & 15);
        bfrag[(size_t)head * FRAGH + (size_t)(((t * 4 + ks) * 64 + lane) * 8 + j)] =
            __float2bfloat16(s);
    } else {
        int r = (int)(o - KSBASE);
        int head = r >> 7, k = r & 127;
        int ks = k >> 5, lg = (k >> 3) & 3, j = k & 7;
        bfrag[(size_t)head * FRAGH + (size_t)(((16 + ks) * 64 + lg * 16) * 8 + j)] =
            __float2bfloat16(s);
    }
}

// ---------------- Pass 2: out = (q_cs @ kv_ext) * norm via MFMA ----------------
__global__ __launch_bounds__(256) void cosformer_out_mfma(
    const float* __restrict__ Q, const __hip_bfloat16* __restrict__ bfrag,
    float* __restrict__ out)
{
    __shared__ __hip_bfloat16 sb[FRAGH];   // 20 KB, fragment-linear
    const int head = blockIdx.x >> 3;
    const int tile = blockIdx.x & 7;
    const int tid  = threadIdx.x;

    {
        const float4* src = (const float4*)(bfrag + (size_t)head * FRAGH);
        float4* dst = (float4*)sb;
        #pragma unroll
        for (int i = 0; i < 5; ++i) dst[tid + 256 * i] = src[tid + 256 * i];
    }

    const int lane = tid & 63;
    const int w    = tid >> 6;
    const int mrow = lane & 15;
    const int kgrp = lane >> 4;

    const float* Qb = Q + (size_t)head * SEQ * DIM;
    float*       Ob = out + (size_t)head * SEQ * DIM;
    const int rowblk = tile * 512;

    float4 qb[2][4];
    #pragma unroll
    for (int m = 0; m < 2; ++m) {
        const float4* qr = (const float4*)(Qb + (size_t)(rowblk + w * 32 + m * 16 + mrow) * DIM);
        qb[m][0] = qr[kgrp * 2];
        qb[m][1] = qr[kgrp * 2 + 1];
        qb[m][2] = qr[8 + kgrp * 2];
        qb[m][3] = qr[8 + kgrp * 2 + 1];
    }

    __syncthreads();

    #pragma unroll
    for (int g = 0; g < 4; ++g) {
        const int base = rowblk + (g * 4 + w) * 32;

        bf16x8v af[2][4];
        #pragma unroll
        for (int m = 0; m < 2; ++m) {
            int arow = base + m * 16 + mrow;
            float ang = 1.5707963267948966f * (float)(arow + 1) / (float)SEQ;
            float sn, cn;
            __sincosf(ang, &sn, &cn);
            float crs = cn * 0.125f, srs = sn * 0.125f;
            float lo[8] = {qb[m][0].x, qb[m][0].y, qb[m][0].z, qb[m][0].w,
                           qb[m][1].x, qb[m][1].y, qb[m][1].z, qb[m][1].w};
            float hi[8] = {qb[m][2].x, qb[m][2].y, qb[m][2].z, qb[m][2].w,
                           qb[m][3].x, qb[m][3].y, qb[m][3].z, qb[m][3].w};
            #pragma unroll
            for (int j = 0; j < 8; ++j) {
                float rl = fmaxf(lo[j], 0.f);
                float rh = fmaxf(hi[j], 0.f);
                af[m][0][j] = (__bf16)(rl * crs);
                af[m][1][j] = (__bf16)(rh * crs);
                af[m][2][j] = (__bf16)(rl * srs);
                af[m][3][j] = (__bf16)(rh * srs);
            }
        }

        if (g < 3) {
            #pragma unroll
            for (int m = 0; m < 2; ++m) {
                const float4* qr = (const float4*)(Qb + (size_t)(rowblk + ((g + 1) * 4 + w) * 32 + m * 16 + mrow) * DIM);
                qb[m][0] = qr[kgrp * 2];
                qb[m][1] = qr[kgrp * 2 + 1];
                qb[m][2] = qr[8 + kgrp * 2];
                qb[m][3] = qr[8 + kgrp * 2 + 1];
            }
        }

        f32x4v acc[2][5];
        #pragma unroll
        for (int m = 0; m < 2; ++m)
            #pragma unroll
            for (int t = 0; t < 5; ++t)
                acc[m][t] = (f32x4v){0.f, 0.f, 0.f, 0.f};

        #pragma unroll
        for (int t = 0; t < 5; ++t)
            #pragma unroll
            for (int ks = 0; ks < 4; ++ks) {
                bf16x8v bf = *(const bf16x8v*)&sb[(size_t)(((t * 4 + ks) * 64 + lane) * 8)];
                acc[0][t] = mfma16(af[0][ks], bf, acc[0][t]);
                acc[1][t] = mfma16(af[1][ks], bf, acc[1][t]);
            }

        #pragma unroll
        for (int m = 0; m < 2; ++m) {
            #pragma unroll
            for (int r = 0; r < 4; ++r) {
                float den = __shfl(acc[m][4][r], lane & 48, 64);
                float invd = 1.0f / fmaxf(den, 1e-6f);
                int row = base + m * 16 + kgrp * 4 + r;
                float* op = Ob + (size_t)row * DIM + mrow;
                op[0]  = acc[m][0][r] * invd;
                op[16] = acc[m][1][r] * invd;
                op[32] = acc[m][2][r] * invd;
                op[48] = acc[m][3][r] * invd;
            }
        }
    }
}

extern "C" void kernel_launch(void* const* d_in, const int* in_sizes, int n_in,
                              void* d_out, int out_size, void* d_ws, size_t ws_size,
                              hipStream_t stream) {
    const float* Q = (const float*)d_in[0];
    const float* K = (const float*)d_in[1];
    const float* V = (const float*)d_in[2];
    float* out = (float*)d_out;
    float* ws  = (float*)d_ws;

    const size_t frag_bytes = (size_t)FRAGH * BHN * sizeof(__hip_bfloat16);
    const size_t need_full  = (size_t)NCHUNK * STRIDE_C * sizeof(float) + frag_bytes;

    if (ws_size >= need_full) {
        float* part = ws;
        __hip_bfloat16* bfrag = (__hip_bfloat16*)(ws + (size_t)NCHUNK * STRIDE_C);
        hipMemsetAsync(bfrag, 0, frag_bytes, stream);
        hipLaunchKernelGGL((cosformer_kv_mfma<0>), dim3(BHN * NCHUNK), dim3(512), 0, stream,
                           K, V, part);
        hipLaunchKernelGGL((reduce_pack<NCHUNK>), dim3((int)(STRIDE_C / 256)), dim3(256), 0, stream,
                           part, bfrag);
        hipLaunchKernelGGL(cosformer_out_mfma, dim3(BHN * 8), dim3(256), 0, stream,
                           Q, bfrag, out);
    } else {
        float* part = ws;
        __hip_bfloat16* bfrag = (__hip_bfloat16*)(ws + STRIDE_C);
        hipMemsetAsync(part, 0, STRIDE_C * sizeof(float), stream);
        hipMemsetAsync(bfrag, 0, frag_bytes, stream);
        hipLaunchKernelGGL((cosformer_kv_mfma<1>), dim3(BHN * NCHUNK), dim3(512), 0, stream,
                           K, V, part);
        hipLaunchKernelGGL((reduce_pack<1>), dim3((int)(STRIDE_C / 256)), dim3(256), 0, stream,
                           part, bfrag);
        hipLaunchKernelGGL(cosformer_out_mfma, dim3(BHN * 8), dim3(256), 0, stream,
                           Q, bfrag, out);
    }
}

// Round 9
// 69.076 us; speedup vs baseline: 6.1760x; 1.0140x over previous
//
#include <hip/hip_runtime.h>
#include <hip/hip_bf16.h>
#include <math.h>

#define BHN    64
#define SEQ    4096
#define DIM    64
#define NCHUNK 8
#define CHUNK  (SEQ / NCHUNK)        // 512 rows per pass-1 block
#define KSTEP  64                    // s-rows staged per iteration
#define NIT    (CHUNK / KSTEP)       // 8 iterations
#define KVF    (128 * DIM)           // 8192 floats of kv per head
#define STRIDE_C ((size_t)BHN * KVF + (size_t)BHN * 128)   // 532480 floats
#define KSBASE ((size_t)BHN * KVF)   // 524288
#define FRAGH  10240                 // bf16 per head: 5 t * 4 ks * 64 lanes * 8 j
#define LPAD   72                    // LDS row pitch (ushorts); rows 144B = 16B aligned

typedef __bf16 bf16x8v __attribute__((ext_vector_type(8)));
typedef float  f32x4v  __attribute__((ext_vector_type(4)));

__device__ inline f32x4v mfma16(bf16x8v a, bf16x8v b, f32x4v c) {
    return __builtin_amdgcn_mfma_f32_16x16x32_bf16(a, b, c, 0, 0, 0);
}

__device__ inline unsigned pk2(float a, float b) {
    __hip_bfloat162 t(__float2bfloat16(a), __float2bfloat16(b));
    return *(unsigned*)&t;
}

// Raw workgroup barrier WITHOUT the compiler's vmcnt(0) drain:
// waits only on LDS ops (cross-wave LDS producer->consumer), leaves
// global loads in flight across the barrier (T4 counted-vmcnt mechanism).
__device__ __forceinline__ void barrier_noflush() {
    asm volatile("s_waitcnt lgkmcnt(0)" ::: "memory");
    __builtin_amdgcn_s_barrier();
    asm volatile("" ::: "memory");
}

// XOR swizzle on u32 column index (32 cols of s-pairs per d-row).
__device__ inline int swz(int d, int col) { return col ^ (4 * ((d >> 2) & 7)); }

// ------- Pass 1 (MFMA): partial kv/ksum per (head, chunk) -------
// kv[f][m] = sum_s k_cs[s][f] * V[s][m];  ksum[f] via ones-column N-tile.
// 512 threads = 8 waves; wave w owns feature tile w (cos tiles 0-3, sin 4-7).
// NIT=8; LDS double-buffer (1 barrier/iter); 3 register load sets.
// Load schedule: prologue L0,L1,L2, W0, L3; loop it issues L(it+4).
// Barriers are raw (no global-load drain) so prefetch crosses them.
template<int USE_ATOMIC>
__global__ __launch_bounds__(512) void cosformer_kv_mfma(
    const float* __restrict__ K, const float* __restrict__ V,
    float* __restrict__ part)
{
    __shared__ ushort ktc[2][64][LPAD];   // relu(K)*cos, transposed [d][s], bf16
    __shared__ ushort kts[2][64][LPAD];   // relu(K)*sin
    __shared__ ushort vtt[2][64][LPAD];   // V, transposed [m][s], bf16

    const int bh    = blockIdx.x / NCHUNK;
    const int chunk = blockIdx.x % NCHUNK;
    const int row0  = chunk * CHUNK;
    const float* Kb = K + (size_t)bh * SEQ * DIM;
    const float* Vb = V + (size_t)bh * SEQ * DIM;

    const int tid = threadIdx.x;
    // staging: d-fast (coalesced): 16 threads cover one 64-float row
    const int dq = (tid & 15) * 4;   // d-block of 4
    const int g  = tid >> 4;         // s-pair index 0..31 (rows 2g, 2g+1)
    // fragments
    const int lane = tid & 63;
    const int w    = tid >> 6;       // 0..7
    const int frow = lane & 15;
    const int kgrp = lane >> 4;

    f32x4v acc[5];
    #pragma unroll
    for (int t = 0; t < 5; ++t) acc[t] = (f32x4v){0.f, 0.f, 0.f, 0.f};

    bf16x8v onef;
    #pragma unroll
    for (int j = 0; j < 8; ++j) onef[j] = (frow == 0) ? (__bf16)1.0f : (__bf16)0.0f;

    // three register staging sets (16 VGPR each)
    float4 sA[4], sB[4], sC[4];

    auto LOADS = [&](int it, float4* r) {
        const float* kp = Kb + (size_t)(row0 + it * KSTEP + 2 * g) * DIM + dq;
        const float* vp = Vb + (size_t)(row0 + it * KSTEP + 2 * g) * DIM + dq;
        r[0] = *(const float4*)kp;
        r[1] = *(const float4*)(kp + DIM);
        r[2] = *(const float4*)vp;
        r[3] = *(const float4*)(vp + DIM);
    };

    auto WRITES = [&](int it, const float4* r, int buf) {
        const int l0 = row0 + it * KSTEP + 2 * g;
        const float CC = 1.5707963267948966f / (float)SEQ;
        float s0v, c0, s1v, c1;
        __sincosf(CC * (float)(l0 + 1), &s0v, &c0);
        __sincosf(CC * (float)(l0 + 2), &s1v, &c1);
        float k0[4] = {r[0].x, r[0].y, r[0].z, r[0].w};
        float k1[4] = {r[1].x, r[1].y, r[1].z, r[1].w};
        float v0[4] = {r[2].x, r[2].y, r[2].z, r[2].w};
        float v1[4] = {r[3].x, r[3].y, r[3].z, r[3].w};
        #pragma unroll
        for (int i = 0; i < 4; ++i) {
            const int d = dq + i;
            const int c = swz(d, g);
            float r0 = fmaxf(k0[i], 0.f), r1 = fmaxf(k1[i], 0.f);
            ((unsigned*)&ktc[buf][d][0])[c] = pk2(r0 * c0,  r1 * c1);
            ((unsigned*)&kts[buf][d][0])[c] = pk2(r0 * s0v, r1 * s1v);
            ((unsigned*)&vtt[buf][d][0])[c] = pk2(v0[i],    v1[i]);
        }
    };

    // set index for load/stage i is i%3 (A,B,C rotating)
    auto LOADS_SEL = [&](int it) {
        int sel = it % 3;
        if (sel == 0) LOADS(it, sA);
        else if (sel == 1) LOADS(it, sB);
        else LOADS(it, sC);
    };
    auto WRITES_SEL = [&](int it, int buf) {
        int sel = it % 3;
        if (sel == 0) WRITES(it, sA, buf);
        else if (sel == 1) WRITES(it, sB, buf);
        else WRITES(it, sC, buf);
    };

    // prologue: one cold stall (W0 waits on L0) while L1,L2 fly;
    // set A is freed by W0 and immediately reloaded with tile 3.
    LOADS_SEL(0);
    LOADS_SEL(1);
    LOADS_SEL(2);
    WRITES_SEL(0, 0);
    LOADS_SEL(3);
    barrier_noflush();

    const int d0 = (w & 3) * 16 + frow;

    #pragma unroll
    for (int it = 0; it < NIT; ++it) {
        const int buf = it & 1;
        const ushort (*ap)[LPAD] = (w < 4) ? ktc[buf] : kts[buf];
        const ushort (*bp)[LPAD] = vtt[buf];
        #pragma unroll
        for (int ks = 0; ks < 2; ++ks) {
            const int cb = ks * 16 + kgrp * 4;   // u32 col base (= s-offset/2)
            bf16x8v a = *(const bf16x8v*)&ap[d0][2 * swz(d0, cb)];
            #pragma unroll
            for (int nt = 0; nt < 4; ++nt) {
                const int dn = nt * 16 + frow;
                bf16x8v b = *(const bf16x8v*)&bp[dn][2 * swz(dn, cb)];
                acc[nt] = mfma16(a, b, acc[nt]);
            }
            acc[4] = mfma16(a, onef, acc[4]);
        }
        if (it + 1 < NIT) {
            // stage next tile into the other LDS buffer; its loads were
            // issued >=1 full iteration ago (counted vmcnt, not drained);
            // then refill the freed register set.
            WRITES_SEL(it + 1, buf ^ 1);
            if (it + 4 < NIT) LOADS_SEL(it + 4);
        }
        barrier_noflush();   // next buffer staged; readers of buf done
    }

    // epilogue (C/D: col=lane&15, row=(lane>>4)*4+reg)
    const int fb = w * 16 + kgrp * 4;
    if (USE_ATOMIC) {
        float* pb = part + (size_t)bh * KVF;
        float* ps = part + KSBASE + bh * 128;
        #pragma unroll
        for (int nt = 0; nt < 4; ++nt)
            #pragma unroll
            for (int r = 0; r < 4; ++r)
                atomicAdd(&pb[(size_t)(fb + r) * DIM + nt * 16 + frow], acc[nt][r]);
        if (frow == 0)
            #pragma unroll
            for (int r = 0; r < 4; ++r) atomicAdd(&ps[fb + r], acc[4][r]);
    } else {
        float* pb = part + STRIDE_C * chunk + (size_t)bh * KVF;
        float* ps = part + STRIDE_C * chunk + KSBASE + bh * 128;
        #pragma unroll
        for (int nt = 0; nt < 4; ++nt)
            #pragma unroll
            for (int r = 0; r < 4; ++r)
                pb[(size_t)(fb + r) * DIM + nt * 16 + frow] = acc[nt][r];
        if (frow == 0)
            #pragma unroll
            for (int r = 0; r < 4; ++r) ps[fb + r] = acc[4][r];
    }
}

// ------- Reduce + pack into bf16 B-fragment layout for pass-2 MFMA -------
// bfrag[head][t][ks][lane][j]: B[k][n], k=ks*32+(lane>>4)*8+j, n=t*16+(lane&15)
// t=0..3: kv columns; t=4 col 0: ksum (denominator), other cols zero (memset).
template<int NC>
__global__ __launch_bounds__(256) void reduce_pack(
    const float* __restrict__ part, __hip_bfloat16* __restrict__ bfrag)
{
    size_t o = (size_t)blockIdx.x * 256 + threadIdx.x;
    float s = 0.f;
    #pragma unroll
    for (int c = 0; c < NC; ++c) s += part[(size_t)c * STRIDE_C + o];
    if (o < KSBASE) {
        int head = (int)(o >> 13);
        int r = (int)(o & 8191);
        int k = r >> 6, n = r & 63;
        int t = n >> 4, ks = k >> 5, lg = (k >> 3) & 3, j = k & 7;
        int lane = lg * 16 + (n & 15);
        bfrag[(size_t)head * FRAGH + (size_t)(((t * 4 + ks) * 64 + lane) * 8 + j)] =
            __float2bfloat16(s);
    } else {
        int r = (int)(o - KSBASE);
        int head = r >> 7, k = r & 127;
        int ks = k >> 5, lg = (k >> 3) & 3, j = k & 7;
        bfrag[(size_t)head * FRAGH + (size_t)(((16 + ks) * 64 + lg * 16) * 8 + j)] =
            __float2bfloat16(s);
    }
}

// ---------------- Pass 2: out = (q_cs @ kv_ext) * norm via MFMA ----------------
__global__ __launch_bounds__(256) void cosformer_out_mfma(
    const float* __restrict__ Q, const __hip_bfloat16* __restrict__ bfrag,
    float* __restrict__ out)
{
    __shared__ __hip_bfloat16 sb[FRAGH];   // 20 KB, fragment-linear
    const int head = blockIdx.x >> 3;
    const int tile = blockIdx.x & 7;
    const int tid  = threadIdx.x;

    {
        const float4* src = (const float4*)(bfrag + (size_t)head * FRAGH);
        float4* dst = (float4*)sb;
        #pragma unroll
        for (int i = 0; i < 5; ++i) dst[tid + 256 * i] = src[tid + 256 * i];
    }

    const int lane = tid & 63;
    const int w    = tid >> 6;
    const int mrow = lane & 15;
    const int kgrp = lane >> 4;

    const float* Qb = Q + (size_t)head * SEQ * DIM;
    float*       Ob = out + (size_t)head * SEQ * DIM;
    const int rowblk = tile * 512;

    float4 qb[2][4];
    #pragma unroll
    for (int m = 0; m < 2; ++m) {
        const float4* qr = (const float4*)(Qb + (size_t)(rowblk + w * 32 + m * 16 + mrow) * DIM);
        qb[m][0] = qr[kgrp * 2];
        qb[m][1] = qr[kgrp * 2 + 1];
        qb[m][2] = qr[8 + kgrp * 2];
        qb[m][3] = qr[8 + kgrp * 2 + 1];
    }

    barrier_noflush();   // sb staged; q loads stay in flight

    #pragma unroll
    for (int g = 0; g < 4; ++g) {
        const int base = rowblk + (g * 4 + w) * 32;

        bf16x8v af[2][4];
        #pragma unroll
        for (int m = 0; m < 2; ++m) {
            int arow = base + m * 16 + mrow;
            float ang = 1.5707963267948966f * (float)(arow + 1) / (float)SEQ;
            float sn, cn;
            __sincosf(ang, &sn, &cn);
            float crs = cn * 0.125f, srs = sn * 0.125f;
            float lo[8] = {qb[m][0].x, qb[m][0].y, qb[m][0].z, qb[m][0].w,
                           qb[m][1].x, qb[m][1].y, qb[m][1].z, qb[m][1].w};
            float hi[8] = {qb[m][2].x, qb[m][2].y, qb[m][2].z, qb[m][2].w,
                           qb[m][3].x, qb[m][3].y, qb[m][3].z, qb[m][3].w};
            #pragma unroll
            for (int j = 0; j < 8; ++j) {
                float rl = fmaxf(lo[j], 0.f);
                float rh = fmaxf(hi[j], 0.f);
                af[m][0][j] = (__bf16)(rl * crs);
                af[m][1][j] = (__bf16)(rh * crs);
                af[m][2][j] = (__bf16)(rl * srs);
                af[m][3][j] = (__bf16)(rh * srs);
            }
        }

        if (g < 3) {
            #pragma unroll
            for (int m = 0; m < 2; ++m) {
                const float4* qr = (const float4*)(Qb + (size_t)(rowblk + ((g + 1) * 4 + w) * 32 + m * 16 + mrow) * DIM);
                qb[m][0] = qr[kgrp * 2];
                qb[m][1] = qr[kgrp * 2 + 1];
                qb[m][2] = qr[8 + kgrp * 2];
                qb[m][3] = qr[8 + kgrp * 2 + 1];
            }
        }

        f32x4v acc[2][5];
        #pragma unroll
        for (int m = 0; m < 2; ++m)
            #pragma unroll
            for (int t = 0; t < 5; ++t)
                acc[m][t] = (f32x4v){0.f, 0.f, 0.f, 0.f};

        #pragma unroll
        for (int t = 0; t < 5; ++t)
            #pragma unroll
            for (int ks = 0; ks < 4; ++ks) {
                bf16x8v bf = *(const bf16x8v*)&sb[(size_t)(((t * 4 + ks) * 64 + lane) * 8)];
                acc[0][t] = mfma16(af[0][ks], bf, acc[0][t]);
                acc[1][t] = mfma16(af[1][ks], bf, acc[1][t]);
            }

        #pragma unroll
        for (int m = 0; m < 2; ++m) {
            #pragma unroll
            for (int r = 0; r < 4; ++r) {
                float den = __shfl(acc[m][4][r], lane & 48, 64);
                float invd = 1.0f / fmaxf(den, 1e-6f);
                int row = base + m * 16 + kgrp * 4 + r;
                float* op = Ob + (size_t)row * DIM + mrow;
                op[0]  = acc[m][0][r] * invd;
                op[16] = acc[m][1][r] * invd;
                op[32] = acc[m][2][r] * invd;
                op[48] = acc[m][3][r] * invd;
            }
        }
    }
}

extern "C" void kernel_launch(void* const* d_in, const int* in_sizes, int n_in,
                              void* d_out, int out_size, void* d_ws, size_t ws_size,
                              hipStream_t stream) {
    const float* Q = (const float*)d_in[0];
    const float* K = (const float*)d_in[1];
    const float* V = (const float*)d_in[2];
    float* out = (float*)d_out;
    float* ws  = (float*)d_ws;

    const size_t frag_bytes = (size_t)FRAGH * BHN * sizeof(__hip_bfloat16);
    const size_t need_full  = (size_t)NCHUNK * STRIDE_C * sizeof(float) + frag_bytes;

    if (ws_size >= need_full) {
        float* part = ws;
        __hip_bfloat16* bfrag = (__hip_bfloat16*)(ws + (size_t)NCHUNK * STRIDE_C);
        hipMemsetAsync(bfrag, 0, frag_bytes, stream);
        hipLaunchKernelGGL((cosformer_kv_mfma<0>), dim3(BHN * NCHUNK), dim3(512), 0, stream,
                           K, V, part);
        hipLaunchKernelGGL((reduce_pack<NCHUNK>), dim3((int)(STRIDE_C / 256)), dim3(256), 0, stream,
                           part, bfrag);
        hipLaunchKernelGGL(cosformer_out_mfma, dim3(BHN * 8), dim3(256), 0, stream,
                           Q, bfrag, out);
    } else {
        float* part = ws;
        __hip_bfloat16* bfrag = (__hip_bfloat16*)(ws + STRIDE_C);
        hipMemsetAsync(part, 0, STRIDE_C * sizeof(float), stream);
        hipMemsetAsync(bfrag, 0, frag_bytes, stream);
        hipLaunchKernelGGL((cosformer_kv_mfma<1>), dim3(BHN * NCHUNK), dim3(512), 0, stream,
                           K, V, part);
        hipLaunchKernelGGL((reduce_pack<1>), dim3((int)(STRIDE_C / 256)), dim3(256), 0, stream,
                           part, bfrag);
        hipLaunchKernelGGL(cosformer_out_mfma, dim3(BHN * 8), dim3(256), 0, stream,
                           Q, bfrag, out);
    }
}